// Round 6
// baseline (475.212 us; speedup 1.0000x reference)
//
#include <hip/hip_runtime.h>
#include <hip/hip_fp16.h>
#include <hip/hip_bf16.h>

constexpr int BB  = 8;
constexpr int NN  = 4096;
constexpr int CC  = 256;
constexpr int CKK = 32;

typedef __attribute__((ext_vector_type(8))) short    short8;  // 8 x bf16 bits
typedef __attribute__((ext_vector_type(8))) _Float16 half8;
typedef __attribute__((ext_vector_type(4))) _Float16 half4;
typedef __attribute__((ext_vector_type(4))) float    f32x4;

__device__ __forceinline__ unsigned short bf16_bits(float v) {
    __hip_bfloat16 h = __float2bfloat16(v);
    return *reinterpret_cast<unsigned short*>(&h);
}
__device__ __forceinline__ float bf16_val(unsigned short u) {
    __hip_bfloat16 h = *reinterpret_cast<__hip_bfloat16*>(&u);
    return __bfloat162float(h);
}

// ---------------------------------------------------------------------------
// K0: transpose + bf16 hi/lo split of all weights into WT[576][256]:
// rows 0..255 = Wh cols, 256..287 = Wf, 288..319 = Wg, 320..575 = Wo.
// ---------------------------------------------------------------------------
__global__ __launch_bounds__(256) void prep_kernel(
    const float* __restrict__ Wf, const float* __restrict__ Wg,
    const float* __restrict__ Wh, const float* __restrict__ Wo,
    unsigned short* __restrict__ WThi, unsigned short* __restrict__ WTlo)
{
    const int n = blockIdx.x;
    const int k = threadIdx.x;
    float v;
    if      (n < 256) v = Wh[k * 256 + n];
    else if (n < 288) v = Wf[k * 32 + (n - 256)];
    else if (n < 320) v = Wg[k * 32 + (n - 288)];
    else              v = Wo[k * 256 + (n - 320)];
    const unsigned short hi = bf16_bits(v);
    WThi[n * 256 + k] = hi;
    WTlo[n * 256 + k] = bf16_bits(v - bf16_val(hi));
}

// ---------------------------------------------------------------------------
// K1: projections as tiled GEMM [32768 x 256] @ [256 x 320].
// Block = 256 M x 64 N (grid 128 x 5); wave = 64M x 64N = 16 acc tiles.
// Software-pipelined k-loop (round-5, kept: small net win).
// ---------------------------------------------------------------------------
__global__ __launch_bounds__(256) void fgh_kernel(
    const float* __restrict__ x,
    const unsigned short* __restrict__ WThi, const unsigned short* __restrict__ WTlo,
    const float* __restrict__ bf, const float* __restrict__ bg,
    const float* __restrict__ bh,
    _Float16* __restrict__ fbuf, _Float16* __restrict__ gbuf,
    _Float16* __restrict__ hhT)
{
    const int tid = threadIdx.x, w = tid >> 6, lane = tid & 63;
    const int ln = lane & 15, lq = lane >> 4;
    const int px0 = blockIdx.x * 256 + w * 64;   // this wave's first pixel
    const int n0  = blockIdx.y * 64;             // output-column base (0..256)

    f32x4 acc[4][4];   // [mt][nt]
    #pragma unroll
    for (int i = 0; i < 4; ++i)
        #pragma unroll
        for (int j = 0; j < 4; ++j) acc[i][j] = {0.f, 0.f, 0.f, 0.f};

    float  rawA[4][8], rawB[4][8];
    short8 Ahi[4], Alo[4], Bhi[4], Blo[4];

    auto loadraw = [&](float (&rw)[4][8], int k0) {
        #pragma unroll
        for (int mt = 0; mt < 4; ++mt) {
            const float* xp = &x[(size_t)(px0 + mt * 16 + ln) * CC + k0 + lq * 8];
            *(float4*)&rw[mt][0] = *(const float4*)xp;
            *(float4*)&rw[mt][4] = *(const float4*)(xp + 4);
        }
    };
    auto loadB = [&](int k0) {
        #pragma unroll
        for (int nt = 0; nt < 4; ++nt) {
            const size_t boff = (size_t)(n0 + nt * 16 + ln) * 256 + k0 + lq * 8;
            Bhi[nt] = *(const short8*)&WThi[boff];
            Blo[nt] = *(const short8*)&WTlo[boff];
        }
    };
    auto convA = [&](float (&rw)[4][8]) {
        #pragma unroll
        for (int mt = 0; mt < 4; ++mt)
            #pragma unroll
            for (int j = 0; j < 8; ++j) {
                const unsigned short h = bf16_bits(rw[mt][j]);
                Ahi[mt][j] = (short)h;
                Alo[mt][j] = (short)bf16_bits(rw[mt][j] - bf16_val(h));
            }
    };
    auto mfmas = [&]() {
        #pragma unroll
        for (int nt = 0; nt < 4; ++nt)
            #pragma unroll
            for (int mt = 0; mt < 4; ++mt) {
                acc[mt][nt] = __builtin_amdgcn_mfma_f32_16x16x32_bf16(Ahi[mt], Bhi[nt], acc[mt][nt], 0, 0, 0);
                acc[mt][nt] = __builtin_amdgcn_mfma_f32_16x16x32_bf16(Ahi[mt], Blo[nt], acc[mt][nt], 0, 0, 0);
                acc[mt][nt] = __builtin_amdgcn_mfma_f32_16x16x32_bf16(Alo[mt], Bhi[nt], acc[mt][nt], 0, 0, 0);
            }
    };

    loadraw(rawA, 0);
    #pragma unroll 1
    for (int t = 0; t < 4; ++t) {
        const int k0 = t * 64;
        loadB(k0);
        loadraw(rawB, k0 + 32);
        convA(rawA);
        mfmas();
        loadB(k0 + 32);
        loadraw(rawA, (k0 + 64) & 255);
        convA(rawB);
        mfmas();
    }

    const int b = px0 >> 12;
    if (blockIdx.y < 4) {
        // hh channels n0..n0+63 -> transposed fp16 store
        #pragma unroll
        for (int nt = 0; nt < 4; ++nt) {
            const int c = n0 + nt * 16 + ln;
            const float bias = bh[c];
            #pragma unroll
            for (int mt = 0; mt < 4; ++mt) {
                half4 hv;
                #pragma unroll
                for (int r = 0; r < 4; ++r) hv[r] = (_Float16)(acc[mt][nt][r] + bias);
                const int npix = (px0 & (NN - 1)) + mt * 16 + lq * 4;
                *(half4*)&hhT[((size_t)(b * CC + c)) * NN + npix] = hv;
            }
        }
    } else {
        // f (nt 0,1), g (nt 2,3): d = (nt&1)*16 + ln
        #pragma unroll
        for (int nt = 0; nt < 4; ++nt) {
            const int d = (nt & 1) * 16 + ln;
            const float bias = (nt < 2) ? bf[d] : bg[d];
            _Float16* dst = (nt < 2) ? fbuf : gbuf;
            #pragma unroll
            for (int mt = 0; mt < 4; ++mt)
                #pragma unroll
                for (int r = 0; r < 4; ++r)
                    dst[(size_t)(px0 + mt * 16 + lq * 4 + r) * CKK + d] =
                        (_Float16)(acc[mt][nt][r] + bias);
        }
    }
}

// ---------------------------------------------------------------------------
// K2: MFMA flash attention, q-split for occupancy.
// Block = 32 q x 256 c of one batch; 4 waves; grid 1024 = 4 blocks/CU.
// q-split is the one parallelism axis with ZERO work duplication (pass-1,
// phase A, exp, PV all scale with q; only L2-hot f/hhT reads re-fetch).
// Occupancy model from r0-r3 evidence: __launch_bounds__ 2nd arg acts as
// runtime max waves/EU ((256,2)+VGPR76 pinned 24% in r3; (256,4) capped
// VGPR at 64 and spilled in r2). So: plain (256) + VGPR<=128 + grid 1024
// -> 4 waves/EU. Bh register dbuf dropped (-32 VGPR, est ~110): at 16
// waves/CU, TLP hides the post-barrier Bh L2 latency; every load is now
// issued after a barrier and consumed before the next, so the barrier
// vmcnt drain never waits on an unconsumed load.
// Per 64-key iter: phase A (2 MFMA S^T for wave's 16 keys x 32 q, exp ->
// fp16 P -> LDS dbuf) | barrier | loadBh + next Af | phase B (16 MFMA PV).
// Rowmax pass-1 identical-instruction trick keeps exp <= 1 (fp16-safe).
// ---------------------------------------------------------------------------
__global__ __launch_bounds__(256) void attn_kernel(
    const _Float16* __restrict__ fbuf, const _Float16* __restrict__ gbuf,
    const _Float16* __restrict__ hhT, float* __restrict__ obuf)
{
    __shared__ _Float16 P[2][32 * 72];   // 9 KB, dbuf
    __shared__ float mxbuf[4][32];
    __shared__ float rsbuf[4][32];

    const int tid = threadIdx.x, w = tid >> 6, lane = tid & 63;
    const int ln = lane & 15, lq = lane >> 4;
    const int b  = blockIdx.x & 7;               // batch == XCD (1024 % 8 == 0)
    const int q0 = (blockIdx.x >> 3) * 32;
    const int cb = w * 64;                       // this wave's channel base

    const f32x4 zero = {0.f, 0.f, 0.f, 0.f};
    constexpr float LOG2E = 1.4426950408889634f;

    // persistent g B-frags: B[k=d][n=q], 2 q-tiles
    half8 Bg[2];
    #pragma unroll
    for (int qt = 0; qt < 2; ++qt)
        Bg[qt] = *(const half8*)&gbuf[(size_t)(b * NN + q0 + qt * 16 + ln) * CKK + lq * 8];

    // base pointers (advance by constants inside loops)
    const _Float16* fb = &fbuf[(size_t)(b * NN + w * 16 + ln) * CKK + lq * 8];
    const _Float16* hb = &hhT[((size_t)(b * CC + cb + ln)) * NN + lq * 8];

    // ---- pass 1: rowmax (wave w covers keys j0 + w*16 + 0..15), pipelined ----
    float mx[2];
    #pragma unroll
    for (int qt = 0; qt < 2; ++qt) mx[qt] = -1e30f;
    half8 Afc = *(const half8*)fb;
    #pragma unroll 1
    for (int j0 = 0; j0 < NN; j0 += 64) {
        const int jn = (j0 + 64 < NN) ? j0 + 64 : j0;
        const half8 Afn = *(const half8*)&fb[(size_t)jn * CKK];
        #pragma unroll
        for (int qt = 0; qt < 2; ++qt) {
            const f32x4 s = __builtin_amdgcn_mfma_f32_16x16x32_f16(Afc, Bg[qt], zero, 0, 0, 0);
            mx[qt] = fmaxf(mx[qt], fmaxf(fmaxf(s[0], s[1]), fmaxf(s[2], s[3])));
        }
        Afc = Afn;
    }
    #pragma unroll
    for (int qt = 0; qt < 2; ++qt) {
        mx[qt] = fmaxf(mx[qt], __shfl_xor(mx[qt], 16));
        mx[qt] = fmaxf(mx[qt], __shfl_xor(mx[qt], 32));
    }
    if (lane < 16) {
        #pragma unroll
        for (int qt = 0; qt < 2; ++qt) mxbuf[w][qt * 16 + ln] = mx[qt];
    }
    __syncthreads();
    float mk[2];   // per-lane: q = qt*16 + ln
    #pragma unroll
    for (int qt = 0; qt < 2; ++qt)
        mk[qt] = LOG2E * fmaxf(fmaxf(mxbuf[0][qt * 16 + ln], mxbuf[1][qt * 16 + ln]),
                               fmaxf(mxbuf[2][qt * 16 + ln], mxbuf[3][qt * 16 + ln]));

    // ---- main loop ----
    f32x4 O[2][4];     // [qt][ct]
    #pragma unroll
    for (int qt = 0; qt < 2; ++qt)
        #pragma unroll
        for (int ct = 0; ct < 4; ++ct) O[qt][ct] = zero;
    float psum[2] = {0.f, 0.f};

    // phase A: S^T -> exp -> P (LDS); identical MFMA to pass 1
    auto phaseA = [&](const half8& Af, _Float16* Pb) {
        #pragma unroll
        for (int qt = 0; qt < 2; ++qt) {
            const f32x4 s = __builtin_amdgcn_mfma_f32_16x16x32_f16(Af, Bg[qt], zero, 0, 0, 0);
            half4 ph;
            float ps = 0.f;
            #pragma unroll
            for (int r = 0; r < 4; ++r) {
                const float p = exp2f(fmaf(s[r], LOG2E, -mk[qt]));
                ps += p;
                ph[r] = (_Float16)p;
            }
            psum[qt] += ps;
            // P[q = qt*16+ln][key = w*16 + lq*4 + r]  (A-layout, pad 72)
            *(half4*)&Pb[(qt * 16 + ln) * 72 + w * 16 + lq * 4] = ph;
        }
    };

    // issue 8 global b128 loads of hhT B-frags for key block j0 (single buf)
    half8 Bh[4][2];
    auto loadBh = [&](int j0) {
        #pragma unroll
        for (int ct = 0; ct < 4; ++ct)
            #pragma unroll
            for (int kh = 0; kh < 2; ++kh)
                Bh[ct][kh] = *(const half8*)&hb[(size_t)ct * 16 * NN + j0 + kh * 32];
    };

    // phase B: PV for this wave's 64 channels, K=64 via 2 K32 halves
    auto phaseB = [&](const _Float16* Pb) {
        __builtin_amdgcn_s_setprio(1);
        #pragma unroll
        for (int qt = 0; qt < 2; ++qt) {
            const half8 Ap0 = *(const half8*)&Pb[(qt * 16 + ln) * 72 + lq * 8];
            const half8 Ap1 = *(const half8*)&Pb[(qt * 16 + ln) * 72 + 32 + lq * 8];
            #pragma unroll
            for (int ct = 0; ct < 4; ++ct) {
                O[qt][ct] = __builtin_amdgcn_mfma_f32_16x16x32_f16(Ap0, Bh[ct][0], O[qt][ct], 0, 0, 0);
                O[qt][ct] = __builtin_amdgcn_mfma_f32_16x16x32_f16(Ap1, Bh[ct][1], O[qt][ct], 0, 0, 0);
            }
        }
        __builtin_amdgcn_s_setprio(0);
    };

    half8 Af0 = *(const half8*)fb;
    half8 Af1;

    #pragma unroll 1
    for (int j0 = 0; j0 < NN; j0 += 128) {
        // --- even 64-key block ---
        phaseA(Af0, P[0]);
        __syncthreads();
        loadBh(j0);                               // post-barrier: consumed in
        Af1 = *(const half8*)&fb[(size_t)(j0 + 64) * CKK];   // this phaseB / next phaseA
        phaseB(P[0]);
        // --- odd 64-key block ---
        phaseA(Af1, P[1]);
        __syncthreads();
        loadBh(j0 + 64);
        if (j0 + 128 < NN) Af0 = *(const half8*)&fb[(size_t)(j0 + 128) * CKK];
        phaseB(P[1]);
    }

    // ---- rowsum merge across waves ----
    #pragma unroll
    for (int qt = 0; qt < 2; ++qt) {
        psum[qt] += __shfl_xor(psum[qt], 16);
        psum[qt] += __shfl_xor(psum[qt], 32);
    }
    if (lane < 16) {
        #pragma unroll
        for (int qt = 0; qt < 2; ++qt) rsbuf[w][qt * 16 + ln] = psum[qt];
    }
    __syncthreads();

    // ---- epilogue: normalize, store (row-indexed q) ----
    #pragma unroll
    for (int qt = 0; qt < 2; ++qt)
        #pragma unroll
        for (int r = 0; r < 4; ++r) {
            const int q = qt * 16 + lq * 4 + r;
            const float rinv = 1.0f / (rsbuf[0][q] + rsbuf[1][q] + rsbuf[2][q] + rsbuf[3][q]);
            #pragma unroll
            for (int ct = 0; ct < 4; ++ct)
                obuf[((size_t)(b * NN + q0 + q)) * CC + cb + ct * 16 + ln] = O[qt][ct][r] * rinv;
        }
}

// ---------------------------------------------------------------------------
// K3: out = gamma * (o @ Wo + bo) + x  as tiled GEMM [32768x256]@[256x256].
// Same software-pipelined k-loop as fgh_kernel. Grid 128 x 4.
// ---------------------------------------------------------------------------
__global__ __launch_bounds__(256) void out_kernel(
    const float* __restrict__ obuf,
    const unsigned short* __restrict__ WThi, const unsigned short* __restrict__ WTlo,
    const float* __restrict__ bo, const float* __restrict__ gamma,
    const float* __restrict__ x, float* __restrict__ out)
{
    const int tid = threadIdx.x, w = tid >> 6, lane = tid & 63;
    const int ln = lane & 15, lq = lane >> 4;
    const int px0 = blockIdx.x * 256 + w * 64;
    const int n0  = blockIdx.y * 64;

    f32x4 acc[4][4];
    #pragma unroll
    for (int i = 0; i < 4; ++i)
        #pragma unroll
        for (int j = 0; j < 4; ++j) acc[i][j] = {0.f, 0.f, 0.f, 0.f};

    float  rawA[4][8], rawB[4][8];
    short8 Ahi[4], Alo[4], Bhi[4], Blo[4];

    auto loadraw = [&](float (&rw)[4][8], int k0) {
        #pragma unroll
        for (int mt = 0; mt < 4; ++mt) {
            const float* op = &obuf[(size_t)(px0 + mt * 16 + ln) * CC + k0 + lq * 8];
            *(float4*)&rw[mt][0] = *(const float4*)op;
            *(float4*)&rw[mt][4] = *(const float4*)(op + 4);
        }
    };
    auto loadB = [&](int k0) {
        #pragma unroll
        for (int nt = 0; nt < 4; ++nt) {
            const size_t boff = (size_t)(320 + n0 + nt * 16 + ln) * 256 + k0 + lq * 8;
            Bhi[nt] = *(const short8*)&WThi[boff];
            Blo[nt] = *(const short8*)&WTlo[boff];
        }
    };
    auto convA = [&](float (&rw)[4][8]) {
        #pragma unroll
        for (int mt = 0; mt < 4; ++mt)
            #pragma unroll
            for (int j = 0; j < 8; ++j) {
                const unsigned short h = bf16_bits(rw[mt][j]);
                Ahi[mt][j] = (short)h;
                Alo[mt][j] = (short)bf16_bits(rw[mt][j] - bf16_val(h));
            }
    };
    auto mfmas = [&]() {
        #pragma unroll
        for (int nt = 0; nt < 4; ++nt)
            #pragma unroll
            for (int mt = 0; mt < 4; ++mt) {
                acc[mt][nt] = __builtin_amdgcn_mfma_f32_16x16x32_bf16(Ahi[mt], Bhi[nt], acc[mt][nt], 0, 0, 0);
                acc[mt][nt] = __builtin_amdgcn_mfma_f32_16x16x32_bf16(Ahi[mt], Blo[nt], acc[mt][nt], 0, 0, 0);
                acc[mt][nt] = __builtin_amdgcn_mfma_f32_16x16x32_bf16(Alo[mt], Bhi[nt], acc[mt][nt], 0, 0, 0);
            }
    };

    loadraw(rawA, 0);
    #pragma unroll 1
    for (int t = 0; t < 4; ++t) {
        const int k0 = t * 64;
        loadB(k0);
        loadraw(rawB, k0 + 32);
        convA(rawA);
        mfmas();
        loadB(k0 + 32);
        loadraw(rawA, (k0 + 64) & 255);
        convA(rawB);
        mfmas();
    }

    const float gm = gamma[0];
    #pragma unroll
    for (int nt = 0; nt < 4; ++nt) {
        const int c = n0 + nt * 16 + ln;
        const float bias = bo[c];
        #pragma unroll
        for (int mt = 0; mt < 4; ++mt)
            #pragma unroll
            for (int r = 0; r < 4; ++r) {
                const size_t idx = (size_t)(px0 + mt * 16 + lq * 4 + r) * CC + c;
                out[idx] = gm * (acc[mt][nt][r] + bias) + x[idx];
            }
    }
}

// ---------------------------------------------------------------------------
extern "C" void kernel_launch(void* const* d_in, const int* in_sizes, int n_in,
                              void* d_out, int out_size, void* d_ws, size_t ws_size,
                              hipStream_t stream)
{
    (void)in_sizes; (void)n_in; (void)out_size; (void)ws_size;

    const float* x     = (const float*)d_in[0];
    const float* Wf    = (const float*)d_in[1];
    const float* bf    = (const float*)d_in[2];
    const float* Wg    = (const float*)d_in[3];
    const float* bg    = (const float*)d_in[4];
    const float* Wh    = (const float*)d_in[5];
    const float* bh    = (const float*)d_in[6];
    const float* Wo    = (const float*)d_in[7];
    const float* bo    = (const float*)d_in[8];
    const float* gamma = (const float*)d_in[9];
    float* out = (float*)d_out;

    // ws: f(2MB) | g(2MB) | hhT(16MB) | o(32MB) | WThi | WTlo (~0.6MB)
    _Float16* fbuf = (_Float16*)d_ws;
    _Float16* gbuf = fbuf + (size_t)BB * NN * CKK;
    _Float16* hhT  = gbuf + (size_t)BB * NN * CKK;
    float*    obuf = (float*)(hhT + (size_t)BB * CC * NN);
    unsigned short* WThi = (unsigned short*)(obuf + (size_t)BB * NN * CC);
    unsigned short* WTlo = WThi + (size_t)576 * 256;

    prep_kernel<<<576, 256, 0, stream>>>(Wf, Wg, Wh, Wo, WThi, WTlo);
    fgh_kernel<<<dim3(BB * NN / 256, 5), 256, 0, stream>>>(x, WThi, WTlo, bf, bg, bh,
                                                           fbuf, gbuf, hhT);
    attn_kernel<<<BB * NN / 32, 256, 0, stream>>>(fbuf, gbuf, hhT, obuf);
    out_kernel<<<dim3(BB * NN / 256, 4), 256, 0, stream>>>(obuf, WThi, WTlo, bo, gamma, x, out);
}

// Round 7
// 329.510 us; speedup vs baseline: 1.4422x; 1.4422x over previous
//
#include <hip/hip_runtime.h>
#include <hip/hip_fp16.h>
#include <hip/hip_bf16.h>

constexpr int BB  = 8;
constexpr int NN  = 4096;
constexpr int CC  = 256;
constexpr int CKK = 32;

typedef __attribute__((ext_vector_type(8))) short    short8;  // 8 x bf16 bits
typedef __attribute__((ext_vector_type(8))) _Float16 half8;
typedef __attribute__((ext_vector_type(4))) _Float16 half4;
typedef __attribute__((ext_vector_type(4))) float    f32x4;

__device__ __forceinline__ unsigned short bf16_bits(float v) {
    __hip_bfloat16 h = __float2bfloat16(v);
    return *reinterpret_cast<unsigned short*>(&h);
}
__device__ __forceinline__ float bf16_val(unsigned short u) {
    __hip_bfloat16 h = *reinterpret_cast<__hip_bfloat16*>(&u);
    return __bfloat162float(h);
}

// ---------------------------------------------------------------------------
// K0: transpose + bf16 hi/lo split of all weights into WT[576][256]:
// rows 0..255 = Wh cols, 256..287 = Wf, 288..319 = Wg, 320..575 = Wo.
// ---------------------------------------------------------------------------
__global__ __launch_bounds__(256) void prep_kernel(
    const float* __restrict__ Wf, const float* __restrict__ Wg,
    const float* __restrict__ Wh, const float* __restrict__ Wo,
    unsigned short* __restrict__ WThi, unsigned short* __restrict__ WTlo)
{
    const int n = blockIdx.x;
    const int k = threadIdx.x;
    float v;
    if      (n < 256) v = Wh[k * 256 + n];
    else if (n < 288) v = Wf[k * 32 + (n - 256)];
    else if (n < 320) v = Wg[k * 32 + (n - 288)];
    else              v = Wo[k * 256 + (n - 320)];
    const unsigned short hi = bf16_bits(v);
    WThi[n * 256 + k] = hi;
    WTlo[n * 256 + k] = bf16_bits(v - bf16_val(hi));
}

// ---------------------------------------------------------------------------
// K1: projections as tiled GEMM [32768 x 256] @ [256 x 320].
// Block = 256 M x 64 N (grid 128 x 5); wave = 64M x 64N = 16 acc tiles.
// Software-pipelined k-loop (round-5 state, kept).
// ---------------------------------------------------------------------------
__global__ __launch_bounds__(256) void fgh_kernel(
    const float* __restrict__ x,
    const unsigned short* __restrict__ WThi, const unsigned short* __restrict__ WTlo,
    const float* __restrict__ bf, const float* __restrict__ bg,
    const float* __restrict__ bh,
    _Float16* __restrict__ fbuf, _Float16* __restrict__ gbuf,
    _Float16* __restrict__ hhT)
{
    const int tid = threadIdx.x, w = tid >> 6, lane = tid & 63;
    const int ln = lane & 15, lq = lane >> 4;
    const int px0 = blockIdx.x * 256 + w * 64;   // this wave's first pixel
    const int n0  = blockIdx.y * 64;             // output-column base (0..256)

    f32x4 acc[4][4];   // [mt][nt]
    #pragma unroll
    for (int i = 0; i < 4; ++i)
        #pragma unroll
        for (int j = 0; j < 4; ++j) acc[i][j] = {0.f, 0.f, 0.f, 0.f};

    float  rawA[4][8], rawB[4][8];
    short8 Ahi[4], Alo[4], Bhi[4], Blo[4];

    auto loadraw = [&](float (&rw)[4][8], int k0) {
        #pragma unroll
        for (int mt = 0; mt < 4; ++mt) {
            const float* xp = &x[(size_t)(px0 + mt * 16 + ln) * CC + k0 + lq * 8];
            *(float4*)&rw[mt][0] = *(const float4*)xp;
            *(float4*)&rw[mt][4] = *(const float4*)(xp + 4);
        }
    };
    auto loadB = [&](int k0) {
        #pragma unroll
        for (int nt = 0; nt < 4; ++nt) {
            const size_t boff = (size_t)(n0 + nt * 16 + ln) * 256 + k0 + lq * 8;
            Bhi[nt] = *(const short8*)&WThi[boff];
            Blo[nt] = *(const short8*)&WTlo[boff];
        }
    };
    auto convA = [&](float (&rw)[4][8]) {
        #pragma unroll
        for (int mt = 0; mt < 4; ++mt)
            #pragma unroll
            for (int j = 0; j < 8; ++j) {
                const unsigned short h = bf16_bits(rw[mt][j]);
                Ahi[mt][j] = (short)h;
                Alo[mt][j] = (short)bf16_bits(rw[mt][j] - bf16_val(h));
            }
    };
    auto mfmas = [&]() {
        #pragma unroll
        for (int nt = 0; nt < 4; ++nt)
            #pragma unroll
            for (int mt = 0; mt < 4; ++mt) {
                acc[mt][nt] = __builtin_amdgcn_mfma_f32_16x16x32_bf16(Ahi[mt], Bhi[nt], acc[mt][nt], 0, 0, 0);
                acc[mt][nt] = __builtin_amdgcn_mfma_f32_16x16x32_bf16(Ahi[mt], Blo[nt], acc[mt][nt], 0, 0, 0);
                acc[mt][nt] = __builtin_amdgcn_mfma_f32_16x16x32_bf16(Alo[mt], Bhi[nt], acc[mt][nt], 0, 0, 0);
            }
    };

    loadraw(rawA, 0);
    #pragma unroll 1
    for (int t = 0; t < 4; ++t) {
        const int k0 = t * 64;
        loadB(k0);
        loadraw(rawB, k0 + 32);
        convA(rawA);
        mfmas();
        loadB(k0 + 32);
        loadraw(rawA, (k0 + 64) & 255);
        convA(rawB);
        mfmas();
    }

    const int b = px0 >> 12;
    if (blockIdx.y < 4) {
        // hh channels n0..n0+63 -> transposed fp16 store
        #pragma unroll
        for (int nt = 0; nt < 4; ++nt) {
            const int c = n0 + nt * 16 + ln;
            const float bias = bh[c];
            #pragma unroll
            for (int mt = 0; mt < 4; ++mt) {
                half4 hv;
                #pragma unroll
                for (int r = 0; r < 4; ++r) hv[r] = (_Float16)(acc[mt][nt][r] + bias);
                const int npix = (px0 & (NN - 1)) + mt * 16 + lq * 4;
                *(half4*)&hhT[((size_t)(b * CC + c)) * NN + npix] = hv;
            }
        }
    } else {
        // f (nt 0,1), g (nt 2,3): d = (nt&1)*16 + ln
        #pragma unroll
        for (int nt = 0; nt < 4; ++nt) {
            const int d = (nt & 1) * 16 + ln;
            const float bias = (nt < 2) ? bf[d] : bg[d];
            _Float16* dst = (nt < 2) ? fbuf : gbuf;
            #pragma unroll
            for (int mt = 0; mt < 4; ++mt)
                #pragma unroll
                for (int r = 0; r < 4; ++r)
                    dst[(size_t)(px0 + mt * 16 + lq * 4 + r) * CKK + d] =
                        (_Float16)(acc[mt][nt][r] + bias);
        }
    }
}

// ---------------------------------------------------------------------------
// K2: MFMA flash attention, 8-wave / 128-key-tile restructure.
// Block = 64 q x 256 c of one batch; 8 waves (512 thr); grid 512.
// Invariants kept from the r1 winner: wave-private 16-key phaseA slice
// (no softmax duplication), channel-split PV (no hhT L2 duplication),
// Bh register-prefetch consumed one iter later, LDS P dbuf -> one barrier
// per key-tile. Changes vs r1: key-tile 64 -> 128 (halves barrier count;
// r6 taught: GROW per-barrier work), waves/CU 8 -> 16 if VGPR <= 128
// (budget: O 32 + Bg 16 + Bh 32 single-buf + Af 16 + Ap 4 transient ~ 120).
// Per 128-key iter:
//   phase A: wave w: S^T for keys j0+w*16 x all 64 q (4 MFMA), exp ->
//            fp16 P -> LDS [64][136] dbuf
//   barrier (1 per 128 keys)
//   phase B: PV for wave's 32 channels, K=128 via 4 K32 steps; Bh for the
//            NEXT iter issued after its consumers (reg reuse, ~300cy flight).
// O accumulation order over keys is bitwise-identical to r1; only the
// psum/rowmax partial grouping differs (fp-rounding-level).
// ---------------------------------------------------------------------------
__global__ __launch_bounds__(512) void attn_kernel(
    const _Float16* __restrict__ fbuf, const _Float16* __restrict__ gbuf,
    const _Float16* __restrict__ hhT, float* __restrict__ obuf)
{
    __shared__ _Float16 P[2][64 * 136];  // 34 KB, dbuf (128 keys + pad 8)
    __shared__ float mxbuf[8][64];
    __shared__ float rsbuf[8][64];

    const int tid = threadIdx.x, w = tid >> 6, lane = tid & 63;
    const int ln = lane & 15, lq = lane >> 4;
    const int b  = blockIdx.x & 7;               // batch == XCD (512 % 8 == 0)
    const int q0 = (blockIdx.x >> 3) * 64;
    const int cb = w * 32;                       // this wave's channel base

    const f32x4 zero = {0.f, 0.f, 0.f, 0.f};
    constexpr float LOG2E = 1.4426950408889634f;

    // persistent g B-frags: B[k=d][n=q], all 64 q
    half8 Bg[4];
    #pragma unroll
    for (int qt = 0; qt < 4; ++qt)
        Bg[qt] = *(const half8*)&gbuf[(size_t)(b * NN + q0 + qt * 16 + ln) * CKK + lq * 8];

    // base pointers
    const _Float16* fb = &fbuf[(size_t)(b * NN + w * 16 + ln) * CKK + lq * 8];
    const _Float16* hb = &hhT[((size_t)(b * CC + cb + ln)) * NN + lq * 8];

    // ---- pass 1: rowmax (wave w covers keys j0 + w*16, j0 step 128) ----
    float mx[4];
    #pragma unroll
    for (int qt = 0; qt < 4; ++qt) mx[qt] = -1e30f;
    half8 Afc = *(const half8*)fb;
    #pragma unroll 1
    for (int j0 = 0; j0 < NN; j0 += 128) {
        const int jn = (j0 + 128 < NN) ? j0 + 128 : j0;
        const half8 Afn = *(const half8*)&fb[(size_t)jn * CKK];
        #pragma unroll
        for (int qt = 0; qt < 4; ++qt) {
            const f32x4 s = __builtin_amdgcn_mfma_f32_16x16x32_f16(Afc, Bg[qt], zero, 0, 0, 0);
            mx[qt] = fmaxf(mx[qt], fmaxf(fmaxf(s[0], s[1]), fmaxf(s[2], s[3])));
        }
        Afc = Afn;
    }
    #pragma unroll
    for (int qt = 0; qt < 4; ++qt) {
        mx[qt] = fmaxf(mx[qt], __shfl_xor(mx[qt], 16));
        mx[qt] = fmaxf(mx[qt], __shfl_xor(mx[qt], 32));
    }
    if (lane < 16) {
        #pragma unroll
        for (int qt = 0; qt < 4; ++qt) mxbuf[w][qt * 16 + ln] = mx[qt];
    }
    __syncthreads();
    float mk[4];   // per-lane: q = qt*16 + ln   (max over 8 waves: exact)
    #pragma unroll
    for (int qt = 0; qt < 4; ++qt) {
        float m = mxbuf[0][qt * 16 + ln];
        #pragma unroll
        for (int ww = 1; ww < 8; ++ww) m = fmaxf(m, mxbuf[ww][qt * 16 + ln]);
        mk[qt] = LOG2E * m;
    }

    // ---- main loop ----
    f32x4 O[4][2];     // [qt][ct]
    #pragma unroll
    for (int qt = 0; qt < 4; ++qt)
        #pragma unroll
        for (int ct = 0; ct < 2; ++ct) O[qt][ct] = zero;
    float psum[4] = {0.f, 0.f, 0.f, 0.f};

    // phase A: S^T -> exp -> P (LDS); identical MFMA to pass 1
    auto phaseA = [&](const half8& Af, _Float16* Pb) {
        #pragma unroll
        for (int qt = 0; qt < 4; ++qt) {
            const f32x4 s = __builtin_amdgcn_mfma_f32_16x16x32_f16(Af, Bg[qt], zero, 0, 0, 0);
            half4 ph;
            float ps = 0.f;
            #pragma unroll
            for (int r = 0; r < 4; ++r) {
                const float p = exp2f(fmaf(s[r], LOG2E, -mk[qt]));
                ps += p;
                ph[r] = (_Float16)p;
            }
            psum[qt] += ps;
            // P[q = qt*16+ln][key = w*16 + lq*4 + r]  (pad-136 row)
            *(half4*)&Pb[(qt * 16 + ln) * 136 + w * 16 + lq * 4] = ph;
        }
    };

    // Bh single register buffer: 2 ct x 4 kh = 8 b128 loads (32 VGPR)
    half8 Bh[2][4];
    auto loadBh = [&](int j0) {
        #pragma unroll
        for (int ct = 0; ct < 2; ++ct)
            #pragma unroll
            for (int kh = 0; kh < 4; ++kh)
                Bh[ct][kh] = *(const half8*)&hb[(size_t)ct * 16 * NN + j0 + kh * 32];
    };

    // phase B: PV for this wave's 32 channels, K=128 via 4 K32 steps.
    // Ap read per kh (4 VGPR transient) to stay under the 128-VGPR cliff.
    auto phaseB = [&](const _Float16* Pb) {
        __builtin_amdgcn_s_setprio(1);
        #pragma unroll
        for (int qt = 0; qt < 4; ++qt) {
            #pragma unroll
            for (int kh = 0; kh < 4; ++kh) {
                const half8 Ap = *(const half8*)&Pb[(qt * 16 + ln) * 136 + kh * 32 + lq * 8];
                O[qt][0] = __builtin_amdgcn_mfma_f32_16x16x32_f16(Ap, Bh[0][kh], O[qt][0], 0, 0, 0);
                O[qt][1] = __builtin_amdgcn_mfma_f32_16x16x32_f16(Ap, Bh[1][kh], O[qt][1], 0, 0, 0);
            }
        }
        __builtin_amdgcn_s_setprio(0);
    };

    // prologue
    half8 Af0 = *(const half8*)fb;
    half8 Af1;
    loadBh(0);

    #pragma unroll 1
    for (int j0 = 0; j0 < NN; j0 += 256) {
        // --- even 128-key tile ---
        phaseA(Af0, P[0]);
        __syncthreads();                          // Bh for this tile already long in flight
        Af1 = *(const half8*)&fb[(size_t)(j0 + 128) * CKK];
        phaseB(P[0]);                             // consumes Bh(j0)
        loadBh(j0 + 128);                         // reg reuse after consumers; flies across
        // --- odd 128-key tile ---                 next phaseA + barrier (~300+ cy)
        phaseA(Af1, P[1]);
        __syncthreads();
        Af0 = *(const half8*)&fb[(size_t)((j0 + 256) & (NN - 1)) * CKK];
        phaseB(P[1]);                             // consumes Bh(j0+128)
        loadBh((j0 + 256) & (NN - 1));            // wrap: harmless redundant read
    }

    // ---- rowsum merge across 8 waves ----
    #pragma unroll
    for (int qt = 0; qt < 4; ++qt) {
        psum[qt] += __shfl_xor(psum[qt], 16);
        psum[qt] += __shfl_xor(psum[qt], 32);
    }
    if (lane < 16) {
        #pragma unroll
        for (int qt = 0; qt < 4; ++qt) rsbuf[w][qt * 16 + ln] = psum[qt];
    }
    __syncthreads();

    // ---- epilogue: normalize, store (row-indexed q) ----
    #pragma unroll
    for (int qt = 0; qt < 4; ++qt)
        #pragma unroll
        for (int r = 0; r < 4; ++r) {
            const int q = qt * 16 + lq * 4 + r;
            float rs = rsbuf[0][q];
            #pragma unroll
            for (int ww = 1; ww < 8; ++ww) rs += rsbuf[ww][q];
            const float rinv = 1.0f / rs;
            #pragma unroll
            for (int ct = 0; ct < 2; ++ct)
                obuf[((size_t)(b * NN + q0 + q)) * CC + cb + ct * 16 + ln] = O[qt][ct][r] * rinv;
        }
}

// ---------------------------------------------------------------------------
// K3: out = gamma * (o @ Wo + bo) + x  as tiled GEMM [32768x256]@[256x256].
// Same software-pipelined k-loop as fgh_kernel. Grid 128 x 4.
// ---------------------------------------------------------------------------
__global__ __launch_bounds__(256) void out_kernel(
    const float* __restrict__ obuf,
    const unsigned short* __restrict__ WThi, const unsigned short* __restrict__ WTlo,
    const float* __restrict__ bo, const float* __restrict__ gamma,
    const float* __restrict__ x, float* __restrict__ out)
{
    const int tid = threadIdx.x, w = tid >> 6, lane = tid & 63;
    const int ln = lane & 15, lq = lane >> 4;
    const int px0 = blockIdx.x * 256 + w * 64;
    const int n0  = blockIdx.y * 64;

    f32x4 acc[4][4];
    #pragma unroll
    for (int i = 0; i < 4; ++i)
        #pragma unroll
        for (int j = 0; j < 4; ++j) acc[i][j] = {0.f, 0.f, 0.f, 0.f};

    float  rawA[4][8], rawB[4][8];
    short8 Ahi[4], Alo[4], Bhi[4], Blo[4];

    auto loadraw = [&](float (&rw)[4][8], int k0) {
        #pragma unroll
        for (int mt = 0; mt < 4; ++mt) {
            const float* op = &obuf[(size_t)(px0 + mt * 16 + ln) * CC + k0 + lq * 8];
            *(float4*)&rw[mt][0] = *(const float4*)op;
            *(float4*)&rw[mt][4] = *(const float4*)(op + 4);
        }
    };
    auto loadB = [&](int k0) {
        #pragma unroll
        for (int nt = 0; nt < 4; ++nt) {
            const size_t boff = (size_t)(320 + n0 + nt * 16 + ln) * 256 + k0 + lq * 8;
            Bhi[nt] = *(const short8*)&WThi[boff];
            Blo[nt] = *(const short8*)&WTlo[boff];
        }
    };
    auto convA = [&](float (&rw)[4][8]) {
        #pragma unroll
        for (int mt = 0; mt < 4; ++mt)
            #pragma unroll
            for (int j = 0; j < 8; ++j) {
                const unsigned short h = bf16_bits(rw[mt][j]);
                Ahi[mt][j] = (short)h;
                Alo[mt][j] = (short)bf16_bits(rw[mt][j] - bf16_val(h));
            }
    };
    auto mfmas = [&]() {
        #pragma unroll
        for (int nt = 0; nt < 4; ++nt)
            #pragma unroll
            for (int mt = 0; mt < 4; ++mt) {
                acc[mt][nt] = __builtin_amdgcn_mfma_f32_16x16x32_bf16(Ahi[mt], Bhi[nt], acc[mt][nt], 0, 0, 0);
                acc[mt][nt] = __builtin_amdgcn_mfma_f32_16x16x32_bf16(Ahi[mt], Blo[nt], acc[mt][nt], 0, 0, 0);
                acc[mt][nt] = __builtin_amdgcn_mfma_f32_16x16x32_bf16(Alo[mt], Bhi[nt], acc[mt][nt], 0, 0, 0);
            }
    };

    loadraw(rawA, 0);
    #pragma unroll 1
    for (int t = 0; t < 4; ++t) {
        const int k0 = t * 64;
        loadB(k0);
        loadraw(rawB, k0 + 32);
        convA(rawA);
        mfmas();
        loadB(k0 + 32);
        loadraw(rawA, (k0 + 64) & 255);
        convA(rawB);
        mfmas();
    }

    const float gm = gamma[0];
    #pragma unroll
    for (int nt = 0; nt < 4; ++nt) {
        const int c = n0 + nt * 16 + ln;
        const float bias = bo[c];
        #pragma unroll
        for (int mt = 0; mt < 4; ++mt)
            #pragma unroll
            for (int r = 0; r < 4; ++r) {
                const size_t idx = (size_t)(px0 + mt * 16 + lq * 4 + r) * CC + c;
                out[idx] = gm * (acc[mt][nt][r] + bias) + x[idx];
            }
    }
}

// ---------------------------------------------------------------------------
extern "C" void kernel_launch(void* const* d_in, const int* in_sizes, int n_in,
                              void* d_out, int out_size, void* d_ws, size_t ws_size,
                              hipStream_t stream)
{
    (void)in_sizes; (void)n_in; (void)out_size; (void)ws_size;

    const float* x     = (const float*)d_in[0];
    const float* Wf    = (const float*)d_in[1];
    const float* bf    = (const float*)d_in[2];
    const float* Wg    = (const float*)d_in[3];
    const float* bg    = (const float*)d_in[4];
    const float* Wh    = (const float*)d_in[5];
    const float* bh    = (const float*)d_in[6];
    const float* Wo    = (const float*)d_in[7];
    const float* bo    = (const float*)d_in[8];
    const float* gamma = (const float*)d_in[9];
    float* out = (float*)d_out;

    // ws: f(2MB) | g(2MB) | hhT(16MB) | o(32MB) | WThi | WTlo (~0.6MB)
    _Float16* fbuf = (_Float16*)d_ws;
    _Float16* gbuf = fbuf + (size_t)BB * NN * CKK;
    _Float16* hhT  = gbuf + (size_t)BB * NN * CKK;
    float*    obuf = (float*)(hhT + (size_t)BB * CC * NN);
    unsigned short* WThi = (unsigned short*)(obuf + (size_t)BB * NN * CC);
    unsigned short* WTlo = WThi + (size_t)576 * 256;

    prep_kernel<<<576, 256, 0, stream>>>(Wf, Wg, Wh, Wo, WThi, WTlo);
    fgh_kernel<<<dim3(BB * NN / 256, 5), 256, 0, stream>>>(x, WThi, WTlo, bf, bg, bh,
                                                           fbuf, gbuf, hhT);
    attn_kernel<<<BB * NN / 64, 512, 0, stream>>>(fbuf, gbuf, hhT, obuf);
    out_kernel<<<dim3(BB * NN / 256, 4), 256, 0, stream>>>(obuf, WThi, WTlo, bo, gamma, x, out);
}

// Round 8
// 306.415 us; speedup vs baseline: 1.5509x; 1.0754x over previous
//
#include <hip/hip_runtime.h>
#include <hip/hip_fp16.h>
#include <hip/hip_bf16.h>

constexpr int BB  = 8;
constexpr int NN  = 4096;
constexpr int CC  = 256;
constexpr int CKK = 32;

typedef __attribute__((ext_vector_type(8))) short    short8;  // 8 x bf16 bits
typedef __attribute__((ext_vector_type(8))) _Float16 half8;
typedef __attribute__((ext_vector_type(4))) _Float16 half4;
typedef __attribute__((ext_vector_type(4))) float    f32x4;

__device__ __forceinline__ unsigned short bf16_bits(float v) {
    __hip_bfloat16 h = __float2bfloat16(v);
    return *reinterpret_cast<unsigned short*>(&h);
}
__device__ __forceinline__ float bf16_val(unsigned short u) {
    __hip_bfloat16 h = *reinterpret_cast<__hip_bfloat16*>(&u);
    return __bfloat162float(h);
}

// ---------------------------------------------------------------------------
// K0: transpose + bf16 hi/lo split of all weights into WT[576][256]:
// rows 0..255 = Wh cols, 256..287 = Wf, 288..319 = Wg, 320..575 = Wo.
// ---------------------------------------------------------------------------
__global__ __launch_bounds__(256) void prep_kernel(
    const float* __restrict__ Wf, const float* __restrict__ Wg,
    const float* __restrict__ Wh, const float* __restrict__ Wo,
    unsigned short* __restrict__ WThi, unsigned short* __restrict__ WTlo)
{
    const int n = blockIdx.x;
    const int k = threadIdx.x;
    float v;
    if      (n < 256) v = Wh[k * 256 + n];
    else if (n < 288) v = Wf[k * 32 + (n - 256)];
    else if (n < 320) v = Wg[k * 32 + (n - 288)];
    else              v = Wo[k * 256 + (n - 320)];
    const unsigned short hi = bf16_bits(v);
    WThi[n * 256 + k] = hi;
    WTlo[n * 256 + k] = bf16_bits(v - bf16_val(hi));
}

// ---------------------------------------------------------------------------
// K1: projections as tiled GEMM [32768 x 256] @ [256 x 320].
// Block = 256 M x 64 N (grid 128 x 5); wave = 64M x 64N = 16 acc tiles.
// Software-pipelined k-loop (round-5 state, kept).
// ---------------------------------------------------------------------------
__global__ __launch_bounds__(256) void fgh_kernel(
    const float* __restrict__ x,
    const unsigned short* __restrict__ WThi, const unsigned short* __restrict__ WTlo,
    const float* __restrict__ bf, const float* __restrict__ bg,
    const float* __restrict__ bh,
    _Float16* __restrict__ fbuf, _Float16* __restrict__ gbuf,
    _Float16* __restrict__ hhT)
{
    const int tid = threadIdx.x, w = tid >> 6, lane = tid & 63;
    const int ln = lane & 15, lq = lane >> 4;
    const int px0 = blockIdx.x * 256 + w * 64;   // this wave's first pixel
    const int n0  = blockIdx.y * 64;             // output-column base (0..256)

    f32x4 acc[4][4];   // [mt][nt]
    #pragma unroll
    for (int i = 0; i < 4; ++i)
        #pragma unroll
        for (int j = 0; j < 4; ++j) acc[i][j] = {0.f, 0.f, 0.f, 0.f};

    float  rawA[4][8], rawB[4][8];
    short8 Ahi[4], Alo[4], Bhi[4], Blo[4];

    auto loadraw = [&](float (&rw)[4][8], int k0) {
        #pragma unroll
        for (int mt = 0; mt < 4; ++mt) {
            const float* xp = &x[(size_t)(px0 + mt * 16 + ln) * CC + k0 + lq * 8];
            *(float4*)&rw[mt][0] = *(const float4*)xp;
            *(float4*)&rw[mt][4] = *(const float4*)(xp + 4);
        }
    };
    auto loadB = [&](int k0) {
        #pragma unroll
        for (int nt = 0; nt < 4; ++nt) {
            const size_t boff = (size_t)(n0 + nt * 16 + ln) * 256 + k0 + lq * 8;
            Bhi[nt] = *(const short8*)&WThi[boff];
            Blo[nt] = *(const short8*)&WTlo[boff];
        }
    };
    auto convA = [&](float (&rw)[4][8]) {
        #pragma unroll
        for (int mt = 0; mt < 4; ++mt)
            #pragma unroll
            for (int j = 0; j < 8; ++j) {
                const unsigned short h = bf16_bits(rw[mt][j]);
                Ahi[mt][j] = (short)h;
                Alo[mt][j] = (short)bf16_bits(rw[mt][j] - bf16_val(h));
            }
    };
    auto mfmas = [&]() {
        #pragma unroll
        for (int nt = 0; nt < 4; ++nt)
            #pragma unroll
            for (int mt = 0; mt < 4; ++mt) {
                acc[mt][nt] = __builtin_amdgcn_mfma_f32_16x16x32_bf16(Ahi[mt], Bhi[nt], acc[mt][nt], 0, 0, 0);
                acc[mt][nt] = __builtin_amdgcn_mfma_f32_16x16x32_bf16(Ahi[mt], Blo[nt], acc[mt][nt], 0, 0, 0);
                acc[mt][nt] = __builtin_amdgcn_mfma_f32_16x16x32_bf16(Alo[mt], Bhi[nt], acc[mt][nt], 0, 0, 0);
            }
    };

    loadraw(rawA, 0);
    #pragma unroll 1
    for (int t = 0; t < 4; ++t) {
        const int k0 = t * 64;
        loadB(k0);
        loadraw(rawB, k0 + 32);
        convA(rawA);
        mfmas();
        loadB(k0 + 32);
        loadraw(rawA, (k0 + 64) & 255);
        convA(rawB);
        mfmas();
    }

    const int b = px0 >> 12;
    if (blockIdx.y < 4) {
        // hh channels n0..n0+63 -> transposed fp16 store
        #pragma unroll
        for (int nt = 0; nt < 4; ++nt) {
            const int c = n0 + nt * 16 + ln;
            const float bias = bh[c];
            #pragma unroll
            for (int mt = 0; mt < 4; ++mt) {
                half4 hv;
                #pragma unroll
                for (int r = 0; r < 4; ++r) hv[r] = (_Float16)(acc[mt][nt][r] + bias);
                const int npix = (px0 & (NN - 1)) + mt * 16 + lq * 4;
                *(half4*)&hhT[((size_t)(b * CC + c)) * NN + npix] = hv;
            }
        }
    } else {
        // f (nt 0,1), g (nt 2,3): d = (nt&1)*16 + ln
        #pragma unroll
        for (int nt = 0; nt < 4; ++nt) {
            const int d = (nt & 1) * 16 + ln;
            const float bias = (nt < 2) ? bf[d] : bg[d];
            _Float16* dst = (nt < 2) ? fbuf : gbuf;
            #pragma unroll
            for (int mt = 0; mt < 4; ++mt)
                #pragma unroll
                for (int r = 0; r < 4; ++r)
                    dst[(size_t)(px0 + mt * 16 + lq * 4 + r) * CKK + d] =
                        (_Float16)(acc[mt][nt][r] + bias);
        }
    }
}

// ---------------------------------------------------------------------------
// K2: MFMA flash attention + FUSED output GEMM.
// Main loop = EXACT round-1/5 structure (160.5 us; 4 structural variants all
// plateaued at ~21% MfmaUtil, so the idle MFMA pipe is used for fusion
// instead). Block = 64 q x 256 c; 4 waves; grid 512.
// Fusion: the block owns o[64 q][256 c] in registers at loop end -- exactly
// the A-panel the out-GEMM needs. Epilogue: normalize O -> stage f32 in LDS
// OF[64][268] (pad 268: row stride 12 mod 32 banks -> only 2-way conflicts,
// free; aliased over the then-dead P buffers; 70.6 KB total, still 2
// blocks/CU) -> barrier -> each wave runs the out_kernel inner loop for its
// 64 output channels: A from LDS + identical hi/lo conv, B = WT rows 320+,
// identical kc order and 3-MFMA sequence, identical bias/gamma/x epilogue.
// Per-element accumulation order unchanged -> bitwise-identical out.
// Deletes: obuf write (32 MB), obuf re-read (128 MB), out_kernel dispatch.
// ---------------------------------------------------------------------------
__global__ __launch_bounds__(256, 2) void attn_kernel(
    const _Float16* __restrict__ fbuf, const _Float16* __restrict__ gbuf,
    const _Float16* __restrict__ hhT,
    const unsigned short* __restrict__ WThi, const unsigned short* __restrict__ WTlo,
    const float* __restrict__ bo, const float* __restrict__ gamma,
    const float* __restrict__ x, float* __restrict__ out)
{
    // OF (epilogue o-staging, f32 [64][268]) aliases P (main-loop dbuf).
    __shared__ __align__(16) float OF[64 * 268];          // 68.6 KB
    _Float16* P0 = (_Float16*)OF;                          // [64*72] fp16
    _Float16* P1 = P0 + 64 * 72;
    __shared__ float mxbuf[4][64];
    __shared__ float rsbuf[4][64];

    const int tid = threadIdx.x, w = tid >> 6, lane = tid & 63;
    const int ln = lane & 15, lq = lane >> 4;
    const int b  = blockIdx.x & 7;               // batch == XCD
    const int q0 = (blockIdx.x >> 3) * 64;
    const int cb = w * 64;                       // this wave's channel base

    const f32x4 zero = {0.f, 0.f, 0.f, 0.f};
    constexpr float LOG2E = 1.4426950408889634f;

    // persistent g B-frags: B[k=d][n=q]
    half8 Bg[4];
    #pragma unroll
    for (int qt = 0; qt < 4; ++qt)
        Bg[qt] = *(const half8*)&gbuf[(size_t)(b * NN + q0 + qt * 16 + ln) * CKK + lq * 8];

    // base pointers (advance by constants inside loops)
    const _Float16* fb = &fbuf[(size_t)(b * NN + w * 16 + ln) * CKK + lq * 8];
    const _Float16* hb = &hhT[((size_t)(b * CC + cb + ln)) * NN + lq * 8];

    // ---- pass 1: rowmax (wave w covers keys j0 + w*16 + 0..15), pipelined ----
    float mx[4];
    #pragma unroll
    for (int qt = 0; qt < 4; ++qt) mx[qt] = -1e30f;
    half8 Afc = *(const half8*)fb;
    #pragma unroll 1
    for (int j0 = 0; j0 < NN; j0 += 64) {
        const int jn = (j0 + 64 < NN) ? j0 + 64 : j0;
        const half8 Afn = *(const half8*)&fb[(size_t)jn * CKK];
        #pragma unroll
        for (int qt = 0; qt < 4; ++qt) {
            const f32x4 s = __builtin_amdgcn_mfma_f32_16x16x32_f16(Afc, Bg[qt], zero, 0, 0, 0);
            mx[qt] = fmaxf(mx[qt], fmaxf(fmaxf(s[0], s[1]), fmaxf(s[2], s[3])));
        }
        Afc = Afn;
    }
    #pragma unroll
    for (int qt = 0; qt < 4; ++qt) {
        mx[qt] = fmaxf(mx[qt], __shfl_xor(mx[qt], 16));
        mx[qt] = fmaxf(mx[qt], __shfl_xor(mx[qt], 32));
    }
    if (lane < 16) {
        #pragma unroll
        for (int qt = 0; qt < 4; ++qt) mxbuf[w][qt * 16 + ln] = mx[qt];
    }
    __syncthreads();
    float mk[4];   // per-lane: q = qt*16 + ln
    #pragma unroll
    for (int qt = 0; qt < 4; ++qt)
        mk[qt] = LOG2E * fmaxf(fmaxf(mxbuf[0][qt * 16 + ln], mxbuf[1][qt * 16 + ln]),
                               fmaxf(mxbuf[2][qt * 16 + ln], mxbuf[3][qt * 16 + ln]));

    // ---- main loop ----
    f32x4 O[4][4];     // [qt][ct]
    #pragma unroll
    for (int qt = 0; qt < 4; ++qt)
        #pragma unroll
        for (int ct = 0; ct < 4; ++ct) O[qt][ct] = zero;
    float psum[4] = {0.f, 0.f, 0.f, 0.f};

    // phase A: S^T -> exp -> P (LDS); identical MFMA to pass 1
    auto phaseA = [&](const half8& Af, _Float16* Pb) {
        #pragma unroll
        for (int qt = 0; qt < 4; ++qt) {
            const f32x4 s = __builtin_amdgcn_mfma_f32_16x16x32_f16(Af, Bg[qt], zero, 0, 0, 0);
            half4 ph;
            float ps = 0.f;
            #pragma unroll
            for (int r = 0; r < 4; ++r) {
                const float p = exp2f(fmaf(s[r], LOG2E, -mk[qt]));
                ps += p;
                ph[r] = (_Float16)p;
            }
            psum[qt] += ps;
            // P[q = qt*16+ln][key = w*16 + lq*4 + r]  (A-layout, pad 72)
            *(half4*)&Pb[(qt * 16 + ln) * 72 + w * 16 + lq * 4] = ph;
        }
    };

    // issue 8 global b128 loads of hhT B-frags for key block j0
    auto loadBh = [&](half8 (&Bh)[4][2], int j0) {
        #pragma unroll
        for (int ct = 0; ct < 4; ++ct)
            #pragma unroll
            for (int kh = 0; kh < 2; ++kh)
                Bh[ct][kh] = *(const half8*)&hb[(size_t)ct * 16 * NN + j0 + kh * 32];
    };

    // phase B: PV for this wave's 64 channels, K=64 via 2 K32 halves
    auto phaseB = [&](const half8 (&Bh)[4][2], const _Float16* Pb) {
        __builtin_amdgcn_s_setprio(1);
        #pragma unroll
        for (int qt = 0; qt < 4; ++qt) {
            const half8 Ap0 = *(const half8*)&Pb[(qt * 16 + ln) * 72 + lq * 8];
            const half8 Ap1 = *(const half8*)&Pb[(qt * 16 + ln) * 72 + 32 + lq * 8];
            #pragma unroll
            for (int ct = 0; ct < 4; ++ct) {
                O[qt][ct] = __builtin_amdgcn_mfma_f32_16x16x32_f16(Ap0, Bh[ct][0], O[qt][ct], 0, 0, 0);
                O[qt][ct] = __builtin_amdgcn_mfma_f32_16x16x32_f16(Ap1, Bh[ct][1], O[qt][ct], 0, 0, 0);
            }
        }
        __builtin_amdgcn_s_setprio(0);
    };

    // prologue: current-iter buffers
    half8 Bh0[4][2], Bh1[4][2];
    half8 Af0, Af1;
    loadBh(Bh0, 0);
    Af0 = *(const half8*)fb;

    #pragma unroll 1
    for (int j0 = 0; j0 < NN; j0 += 128) {
        // --- even 64-key block: uses Bh0/Af0, prefetches Bh1/Af1 ---
        phaseA(Af0, P0);
        __syncthreads();                         // drains Bh0 (issued 1 iter ago)
        loadBh(Bh1, j0 + 64);                    // post-barrier issue: lands during
        Af1 = *(const half8*)&fb[(size_t)(j0 + 64) * CKK];  // phaseB + next phaseA
        phaseB(Bh0, P0);
        // --- odd 64-key block: uses Bh1/Af1, prefetches Bh0/Af0 ---
        phaseA(Af1, P1);
        __syncthreads();
        if (j0 + 128 < NN) {
            loadBh(Bh0, j0 + 128);
            Af0 = *(const half8*)&fb[(size_t)(j0 + 128) * CKK];
        }
        phaseB(Bh1, P1);
    }

    // ---- rowsum merge across waves ----
    #pragma unroll
    for (int qt = 0; qt < 4; ++qt) {
        psum[qt] += __shfl_xor(psum[qt], 16);
        psum[qt] += __shfl_xor(psum[qt], 32);
    }
    if (lane < 16) {
        #pragma unroll
        for (int qt = 0; qt < 4; ++qt) rsbuf[w][qt * 16 + ln] = psum[qt];
    }
    __syncthreads();   // also: all phaseB P-reads done -> P (alias OF) is dead

    // ---- stage normalized o into LDS OF[64][268] (f32, same values the
    //      old obuf held) ----
    #pragma unroll
    for (int qt = 0; qt < 4; ++qt)
        #pragma unroll
        for (int r = 0; r < 4; ++r) {
            const int q = qt * 16 + lq * 4 + r;
            const float rinv = 1.0f / (rsbuf[0][q] + rsbuf[1][q] + rsbuf[2][q] + rsbuf[3][q]);
            #pragma unroll
            for (int ct = 0; ct < 4; ++ct)
                OF[q * 268 + cb + ct * 16 + ln] = O[qt][ct][r] * rinv;
        }
    __syncthreads();

    // ---- fused out-GEMM: out[64 q][256 c] = gamma*(o @ Wo + bo) + x.
    //      Wave w handles out-channels n0 = w*64 .. +63; identical inner
    //      loop to the old out_kernel (bitwise-same accumulation). ----
    {
        const int n0 = w * 64;
        f32x4 acc[4][4];
        #pragma unroll
        for (int i = 0; i < 4; ++i)
            #pragma unroll
            for (int j = 0; j < 4; ++j) acc[i][j] = {0.f, 0.f, 0.f, 0.f};

        short8 Ahi[4], Alo[4];
        #pragma unroll 1
        for (int kc = 0; kc < 8; ++kc) {
            const int k0 = kc * 32;
            #pragma unroll
            for (int mt = 0; mt < 4; ++mt) {
                float av[8];
                *(f32x4*)&av[0] = *(const f32x4*)&OF[(mt * 16 + ln) * 268 + k0 + lq * 8];
                *(f32x4*)&av[4] = *(const f32x4*)&OF[(mt * 16 + ln) * 268 + k0 + lq * 8 + 4];
                #pragma unroll
                for (int j = 0; j < 8; ++j) {
                    const unsigned short h = bf16_bits(av[j]);
                    Ahi[mt][j] = (short)h;
                    Alo[mt][j] = (short)bf16_bits(av[j] - bf16_val(h));
                }
            }
            #pragma unroll
            for (int nt = 0; nt < 4; ++nt) {
                const size_t boff = (size_t)(320 + n0 + nt * 16 + ln) * 256 + k0 + lq * 8;
                const short8 Bhi = *(const short8*)&WThi[boff];
                const short8 Blo = *(const short8*)&WTlo[boff];
                #pragma unroll
                for (int mt = 0; mt < 4; ++mt) {
                    acc[mt][nt] = __builtin_amdgcn_mfma_f32_16x16x32_bf16(Ahi[mt], Bhi, acc[mt][nt], 0, 0, 0);
                    acc[mt][nt] = __builtin_amdgcn_mfma_f32_16x16x32_bf16(Ahi[mt], Blo, acc[mt][nt], 0, 0, 0);
                    acc[mt][nt] = __builtin_amdgcn_mfma_f32_16x16x32_bf16(Alo[mt], Bhi, acc[mt][nt], 0, 0, 0);
                }
            }
        }

        const float gm = gamma[0];
        #pragma unroll
        for (int nt = 0; nt < 4; ++nt) {
            const int c = n0 + nt * 16 + ln;
            const float bias = bo[c];
            #pragma unroll
            for (int mt = 0; mt < 4; ++mt)
                #pragma unroll
                for (int r = 0; r < 4; ++r) {
                    const size_t idx = (size_t)(b * NN + q0 + mt * 16 + lq * 4 + r) * CC + c;
                    out[idx] = gm * (acc[mt][nt][r] + bias) + x[idx];
                }
        }
    }
}

// ---------------------------------------------------------------------------
extern "C" void kernel_launch(void* const* d_in, const int* in_sizes, int n_in,
                              void* d_out, int out_size, void* d_ws, size_t ws_size,
                              hipStream_t stream)
{
    (void)in_sizes; (void)n_in; (void)out_size; (void)ws_size;

    const float* x     = (const float*)d_in[0];
    const float* Wf    = (const float*)d_in[1];
    const float* bf    = (const float*)d_in[2];
    const float* Wg    = (const float*)d_in[3];
    const float* bg    = (const float*)d_in[4];
    const float* Wh    = (const float*)d_in[5];
    const float* bh    = (const float*)d_in[6];
    const float* Wo    = (const float*)d_in[7];
    const float* bo    = (const float*)d_in[8];
    const float* gamma = (const float*)d_in[9];
    float* out = (float*)d_out;

    // ws: f(2MB) | g(2MB) | hhT(16MB) | WThi | WTlo (~0.6MB)
    _Float16* fbuf = (_Float16*)d_ws;
    _Float16* gbuf = fbuf + (size_t)BB * NN * CKK;
    _Float16* hhT  = gbuf + (size_t)BB * NN * CKK;
    unsigned short* WThi = (unsigned short*)(hhT + (size_t)BB * CC * NN);
    unsigned short* WTlo = WThi + (size_t)576 * 256;

    prep_kernel<<<576, 256, 0, stream>>>(Wf, Wg, Wh, Wo, WThi, WTlo);
    fgh_kernel<<<dim3(BB * NN / 256, 5), 256, 0, stream>>>(x, WThi, WTlo, bf, bg, bh,
                                                           fbuf, gbuf, hhT);
    attn_kernel<<<BB * NN / 64, 256, 0, stream>>>(fbuf, gbuf, hhT, WThi, WTlo,
                                                  bo, gamma, x, out);
}

// Round 9
// 298.827 us; speedup vs baseline: 1.5903x; 1.0254x over previous
//
#include <hip/hip_runtime.h>
#include <hip/hip_fp16.h>
#include <hip/hip_bf16.h>

constexpr int BB  = 8;
constexpr int NN  = 4096;
constexpr int CC  = 256;
constexpr int CKK = 32;

typedef __attribute__((ext_vector_type(8))) short    short8;  // 8 x bf16 bits
typedef __attribute__((ext_vector_type(8))) _Float16 half8;
typedef __attribute__((ext_vector_type(4))) _Float16 half4;
typedef __attribute__((ext_vector_type(4))) float    f32x4;

__device__ __forceinline__ unsigned short bf16_bits(float v) {
    __hip_bfloat16 h = __float2bfloat16(v);
    return *reinterpret_cast<unsigned short*>(&h);
}
__device__ __forceinline__ float bf16_val(unsigned short u) {
    __hip_bfloat16 h = *reinterpret_cast<__hip_bfloat16*>(&u);
    return __bfloat162float(h);
}

// ---------------------------------------------------------------------------
// K0: transpose + bf16 hi/lo split of all weights into WT[576][256]:
// rows 0..255 = Wh cols, 256..287 = Wf, 288..319 = Wg, 320..575 = Wo.
// ---------------------------------------------------------------------------
__global__ __launch_bounds__(256) void prep_kernel(
    const float* __restrict__ Wf, const float* __restrict__ Wg,
    const float* __restrict__ Wh, const float* __restrict__ Wo,
    unsigned short* __restrict__ WThi, unsigned short* __restrict__ WTlo)
{
    const int n = blockIdx.x;
    const int k = threadIdx.x;
    float v;
    if      (n < 256) v = Wh[k * 256 + n];
    else if (n < 288) v = Wf[k * 32 + (n - 256)];
    else if (n < 320) v = Wg[k * 32 + (n - 288)];
    else              v = Wo[k * 256 + (n - 320)];
    const unsigned short hi = bf16_bits(v);
    WThi[n * 256 + k] = hi;
    WTlo[n * 256 + k] = bf16_bits(v - bf16_val(hi));
}

// ---------------------------------------------------------------------------
// K1: projections, REPARTITIONED. Old: grid 128x5, each of 5 N-blocks
// re-read the same 32 MB x (~160 MB HBM) at 2.5 ragged blocks/CU; ~120 us
// vs a ~10 us floor. New: 512 blocks (b, q0) -- block computes ALL 320
// output cols for its OWN 64 pixels: x read exactly once (32 MB), B-panels
// (590 KB) L2-resident, exactly 2 blocks/CU, and block (b,q0) writes the
// hhT/f/g region that attn block (b,q0) reads later on the same XCD.
// Wave = 64 px x 80 cols (4 mt x 5 nt acc tiles); 60 MFMA per k-step.
// Per-element kc order + 3-MFMA hi/lo sequence identical -> bitwise-same.
// ---------------------------------------------------------------------------
__global__ __launch_bounds__(256) void fgh_kernel(
    const float* __restrict__ x,
    const unsigned short* __restrict__ WThi, const unsigned short* __restrict__ WTlo,
    const float* __restrict__ bf, const float* __restrict__ bg,
    const float* __restrict__ bh,
    _Float16* __restrict__ fbuf, _Float16* __restrict__ gbuf,
    _Float16* __restrict__ hhT)
{
    const int tid = threadIdx.x, w = tid >> 6, lane = tid & 63;
    const int ln = lane & 15, lq = lane >> 4;
    const int b  = blockIdx.x & 7;               // batch == XCD
    const int q0 = (blockIdx.x >> 3) * 64;
    const size_t px0 = (size_t)b * NN + q0;      // block's 64 pixels
    const int n0 = w * 80;                       // wave's 80 output columns

    f32x4 acc[4][5];   // [mt][nt]
    #pragma unroll
    for (int i = 0; i < 4; ++i)
        #pragma unroll
        for (int j = 0; j < 5; ++j) acc[i][j] = {0.f, 0.f, 0.f, 0.f};

    short8 Ahi[4], Alo[4];
    #pragma unroll 1
    for (int kc = 0; kc < 8; ++kc) {
        const int k0 = kc * 32;
        #pragma unroll
        for (int mt = 0; mt < 4; ++mt) {
            float av[8];
            const float* xp = &x[(px0 + mt * 16 + ln) * CC + k0 + lq * 8];
            *(float4*)&av[0] = *(const float4*)xp;
            *(float4*)&av[4] = *(const float4*)(xp + 4);
            #pragma unroll
            for (int j = 0; j < 8; ++j) {
                const unsigned short h = bf16_bits(av[j]);
                Ahi[mt][j] = (short)h;
                Alo[mt][j] = (short)bf16_bits(av[j] - bf16_val(h));
            }
        }
        #pragma unroll
        for (int nt = 0; nt < 5; ++nt) {
            const size_t boff = (size_t)(n0 + nt * 16 + ln) * 256 + k0 + lq * 8;
            const short8 Bhi = *(const short8*)&WThi[boff];
            const short8 Blo = *(const short8*)&WTlo[boff];
            #pragma unroll
            for (int mt = 0; mt < 4; ++mt) {
                acc[mt][nt] = __builtin_amdgcn_mfma_f32_16x16x32_bf16(Ahi[mt], Bhi, acc[mt][nt], 0, 0, 0);
                acc[mt][nt] = __builtin_amdgcn_mfma_f32_16x16x32_bf16(Ahi[mt], Blo, acc[mt][nt], 0, 0, 0);
                acc[mt][nt] = __builtin_amdgcn_mfma_f32_16x16x32_bf16(Alo[mt], Bhi, acc[mt][nt], 0, 0, 0);
            }
        }
    }

    // stores: c < 256 -> hhT (transposed fp16); 256..287 -> f; 288..319 -> g.
    // c = n0 + nt*16 + ln: wave-uniform branch per nt (boundaries are x16).
    #pragma unroll
    for (int nt = 0; nt < 5; ++nt) {
        const int c = n0 + nt * 16 + ln;
        if (c < 256) {
            const float bias = bh[c];
            #pragma unroll
            for (int mt = 0; mt < 4; ++mt) {
                half4 hv;
                #pragma unroll
                for (int r = 0; r < 4; ++r) hv[r] = (_Float16)(acc[mt][nt][r] + bias);
                *(half4*)&hhT[((size_t)(b * CC + c)) * NN + q0 + mt * 16 + lq * 4] = hv;
            }
        } else {
            const bool isf = (c < 288);
            const int d = isf ? (c - 256) : (c - 288);
            const float bias = isf ? bf[d] : bg[d];
            _Float16* dst = isf ? fbuf : gbuf;
            #pragma unroll
            for (int mt = 0; mt < 4; ++mt)
                #pragma unroll
                for (int r = 0; r < 4; ++r)
                    dst[(px0 + mt * 16 + lq * 4 + r) * CKK + d] =
                        (_Float16)(acc[mt][nt][r] + bias);
        }
    }
}

// ---------------------------------------------------------------------------
// K2: MFMA flash attention + FUSED output GEMM (round-8 state, unchanged:
// 181 us, matched prediction). Block = 64 q x 256 c; 4 waves; grid 512.
// Main loop: phaseA (S^T -> exp -> P LDS dbuf) | barrier | post-barrier Bh
// prefetch | phaseB (PV, register-dbuf Bh). Epilogue: normalize O -> LDS
// OF[64][268] (aliases dead P) -> out_kernel inner loop per wave (64 out
// channels) -> gamma/bias/x epilogue. Bitwise-identical to unfused.
// ---------------------------------------------------------------------------
__global__ __launch_bounds__(256, 2) void attn_kernel(
    const _Float16* __restrict__ fbuf, const _Float16* __restrict__ gbuf,
    const _Float16* __restrict__ hhT,
    const unsigned short* __restrict__ WThi, const unsigned short* __restrict__ WTlo,
    const float* __restrict__ bo, const float* __restrict__ gamma,
    const float* __restrict__ x, float* __restrict__ out)
{
    // OF (epilogue o-staging, f32 [64][268]) aliases P (main-loop dbuf).
    __shared__ __align__(16) float OF[64 * 268];          // 68.6 KB
    _Float16* P0 = (_Float16*)OF;                          // [64*72] fp16
    _Float16* P1 = P0 + 64 * 72;
    __shared__ float mxbuf[4][64];
    __shared__ float rsbuf[4][64];

    const int tid = threadIdx.x, w = tid >> 6, lane = tid & 63;
    const int ln = lane & 15, lq = lane >> 4;
    const int b  = blockIdx.x & 7;               // batch == XCD
    const int q0 = (blockIdx.x >> 3) * 64;
    const int cb = w * 64;                       // this wave's channel base

    const f32x4 zero = {0.f, 0.f, 0.f, 0.f};
    constexpr float LOG2E = 1.4426950408889634f;

    // persistent g B-frags: B[k=d][n=q]
    half8 Bg[4];
    #pragma unroll
    for (int qt = 0; qt < 4; ++qt)
        Bg[qt] = *(const half8*)&gbuf[(size_t)(b * NN + q0 + qt * 16 + ln) * CKK + lq * 8];

    // base pointers (advance by constants inside loops)
    const _Float16* fb = &fbuf[(size_t)(b * NN + w * 16 + ln) * CKK + lq * 8];
    const _Float16* hb = &hhT[((size_t)(b * CC + cb + ln)) * NN + lq * 8];

    // ---- pass 1: rowmax (wave w covers keys j0 + w*16 + 0..15), pipelined ----
    float mx[4];
    #pragma unroll
    for (int qt = 0; qt < 4; ++qt) mx[qt] = -1e30f;
    half8 Afc = *(const half8*)fb;
    #pragma unroll 1
    for (int j0 = 0; j0 < NN; j0 += 64) {
        const int jn = (j0 + 64 < NN) ? j0 + 64 : j0;
        const half8 Afn = *(const half8*)&fb[(size_t)jn * CKK];
        #pragma unroll
        for (int qt = 0; qt < 4; ++qt) {
            const f32x4 s = __builtin_amdgcn_mfma_f32_16x16x32_f16(Afc, Bg[qt], zero, 0, 0, 0);
            mx[qt] = fmaxf(mx[qt], fmaxf(fmaxf(s[0], s[1]), fmaxf(s[2], s[3])));
        }
        Afc = Afn;
    }
    #pragma unroll
    for (int qt = 0; qt < 4; ++qt) {
        mx[qt] = fmaxf(mx[qt], __shfl_xor(mx[qt], 16));
        mx[qt] = fmaxf(mx[qt], __shfl_xor(mx[qt], 32));
    }
    if (lane < 16) {
        #pragma unroll
        for (int qt = 0; qt < 4; ++qt) mxbuf[w][qt * 16 + ln] = mx[qt];
    }
    __syncthreads();
    float mk[4];   // per-lane: q = qt*16 + ln
    #pragma unroll
    for (int qt = 0; qt < 4; ++qt)
        mk[qt] = LOG2E * fmaxf(fmaxf(mxbuf[0][qt * 16 + ln], mxbuf[1][qt * 16 + ln]),
                               fmaxf(mxbuf[2][qt * 16 + ln], mxbuf[3][qt * 16 + ln]));

    // ---- main loop ----
    f32x4 O[4][4];     // [qt][ct]
    #pragma unroll
    for (int qt = 0; qt < 4; ++qt)
        #pragma unroll
        for (int ct = 0; ct < 4; ++ct) O[qt][ct] = zero;
    float psum[4] = {0.f, 0.f, 0.f, 0.f};

    // phase A: S^T -> exp -> P (LDS); identical MFMA to pass 1
    auto phaseA = [&](const half8& Af, _Float16* Pb) {
        #pragma unroll
        for (int qt = 0; qt < 4; ++qt) {
            const f32x4 s = __builtin_amdgcn_mfma_f32_16x16x32_f16(Af, Bg[qt], zero, 0, 0, 0);
            half4 ph;
            float ps = 0.f;
            #pragma unroll
            for (int r = 0; r < 4; ++r) {
                const float p = exp2f(fmaf(s[r], LOG2E, -mk[qt]));
                ps += p;
                ph[r] = (_Float16)p;
            }
            psum[qt] += ps;
            // P[q = qt*16+ln][key = w*16 + lq*4 + r]  (A-layout, pad 72)
            *(half4*)&Pb[(qt * 16 + ln) * 72 + w * 16 + lq * 4] = ph;
        }
    };

    // issue 8 global b128 loads of hhT B-frags for key block j0
    auto loadBh = [&](half8 (&Bh)[4][2], int j0) {
        #pragma unroll
        for (int ct = 0; ct < 4; ++ct)
            #pragma unroll
            for (int kh = 0; kh < 2; ++kh)
                Bh[ct][kh] = *(const half8*)&hb[(size_t)ct * 16 * NN + j0 + kh * 32];
    };

    // phase B: PV for this wave's 64 channels, K=64 via 2 K32 halves
    auto phaseB = [&](const half8 (&Bh)[4][2], const _Float16* Pb) {
        __builtin_amdgcn_s_setprio(1);
        #pragma unroll
        for (int qt = 0; qt < 4; ++qt) {
            const half8 Ap0 = *(const half8*)&Pb[(qt * 16 + ln) * 72 + lq * 8];
            const half8 Ap1 = *(const half8*)&Pb[(qt * 16 + ln) * 72 + 32 + lq * 8];
            #pragma unroll
            for (int ct = 0; ct < 4; ++ct) {
                O[qt][ct] = __builtin_amdgcn_mfma_f32_16x16x32_f16(Ap0, Bh[ct][0], O[qt][ct], 0, 0, 0);
                O[qt][ct] = __builtin_amdgcn_mfma_f32_16x16x32_f16(Ap1, Bh[ct][1], O[qt][ct], 0, 0, 0);
            }
        }
        __builtin_amdgcn_s_setprio(0);
    };

    // prologue: current-iter buffers
    half8 Bh0[4][2], Bh1[4][2];
    half8 Af0, Af1;
    loadBh(Bh0, 0);
    Af0 = *(const half8*)fb;

    #pragma unroll 1
    for (int j0 = 0; j0 < NN; j0 += 128) {
        // --- even 64-key block: uses Bh0/Af0, prefetches Bh1/Af1 ---
        phaseA(Af0, P0);
        __syncthreads();                         // drains Bh0 (issued 1 iter ago)
        loadBh(Bh1, j0 + 64);                    // post-barrier issue: lands during
        Af1 = *(const half8*)&fb[(size_t)(j0 + 64) * CKK];  // phaseB + next phaseA
        phaseB(Bh0, P0);
        // --- odd 64-key block: uses Bh1/Af1, prefetches Bh0/Af0 ---
        phaseA(Af1, P1);
        __syncthreads();
        if (j0 + 128 < NN) {
            loadBh(Bh0, j0 + 128);
            Af0 = *(const half8*)&fb[(size_t)(j0 + 128) * CKK];
        }
        phaseB(Bh1, P1);
    }

    // ---- rowsum merge across waves ----
    #pragma unroll
    for (int qt = 0; qt < 4; ++qt) {
        psum[qt] += __shfl_xor(psum[qt], 16);
        psum[qt] += __shfl_xor(psum[qt], 32);
    }
    if (lane < 16) {
        #pragma unroll
        for (int qt = 0; qt < 4; ++qt) rsbuf[w][qt * 16 + ln] = psum[qt];
    }
    __syncthreads();   // also: all phaseB P-reads done -> P (alias OF) is dead

    // ---- stage normalized o into LDS OF[64][268] (f32, same values the
    //      old obuf held) ----
    #pragma unroll
    for (int qt = 0; qt < 4; ++qt)
        #pragma unroll
        for (int r = 0; r < 4; ++r) {
            const int q = qt * 16 + lq * 4 + r;
            const float rinv = 1.0f / (rsbuf[0][q] + rsbuf[1][q] + rsbuf[2][q] + rsbuf[3][q]);
            #pragma unroll
            for (int ct = 0; ct < 4; ++ct)
                OF[q * 268 + cb + ct * 16 + ln] = O[qt][ct][r] * rinv;
        }
    __syncthreads();

    // ---- fused out-GEMM: out[64 q][256 c] = gamma*(o @ Wo + bo) + x.
    //      Wave w handles out-channels n0 = w*64 .. +63; identical inner
    //      loop to the old out_kernel (bitwise-same accumulation). ----
    {
        const int n0 = w * 64;
        f32x4 acc[4][4];
        #pragma unroll
        for (int i = 0; i < 4; ++i)
            #pragma unroll
            for (int j = 0; j < 4; ++j) acc[i][j] = {0.f, 0.f, 0.f, 0.f};

        short8 Ahi[4], Alo[4];
        #pragma unroll 1
        for (int kc = 0; kc < 8; ++kc) {
            const int k0 = kc * 32;
            #pragma unroll
            for (int mt = 0; mt < 4; ++mt) {
                float av[8];
                *(f32x4*)&av[0] = *(const f32x4*)&OF[(mt * 16 + ln) * 268 + k0 + lq * 8];
                *(f32x4*)&av[4] = *(const f32x4*)&OF[(mt * 16 + ln) * 268 + k0 + lq * 8 + 4];
                #pragma unroll
                for (int j = 0; j < 8; ++j) {
                    const unsigned short h = bf16_bits(av[j]);
                    Ahi[mt][j] = (short)h;
                    Alo[mt][j] = (short)bf16_bits(av[j] - bf16_val(h));
                }
            }
            #pragma unroll
            for (int nt = 0; nt < 4; ++nt) {
                const size_t boff = (size_t)(320 + n0 + nt * 16 + ln) * 256 + k0 + lq * 8;
                const short8 Bhi = *(const short8*)&WThi[boff];
                const short8 Blo = *(const short8*)&WTlo[boff];
                #pragma unroll
                for (int mt = 0; mt < 4; ++mt) {
                    acc[mt][nt] = __builtin_amdgcn_mfma_f32_16x16x32_bf16(Ahi[mt], Bhi, acc[mt][nt], 0, 0, 0);
                    acc[mt][nt] = __builtin_amdgcn_mfma_f32_16x16x32_bf16(Ahi[mt], Blo, acc[mt][nt], 0, 0, 0);
                    acc[mt][nt] = __builtin_amdgcn_mfma_f32_16x16x32_bf16(Alo[mt], Bhi, acc[mt][nt], 0, 0, 0);
                }
            }
        }

        const float gm = gamma[0];
        #pragma unroll
        for (int nt = 0; nt < 4; ++nt) {
            const int c = n0 + nt * 16 + ln;
            const float bias = bo[c];
            #pragma unroll
            for (int mt = 0; mt < 4; ++mt)
                #pragma unroll
                for (int r = 0; r < 4; ++r) {
                    const size_t idx = (size_t)(b * NN + q0 + mt * 16 + lq * 4 + r) * CC + c;
                    out[idx] = gm * (acc[mt][nt][r] + bias) + x[idx];
                }
        }
    }
}

// ---------------------------------------------------------------------------
extern "C" void kernel_launch(void* const* d_in, const int* in_sizes, int n_in,
                              void* d_out, int out_size, void* d_ws, size_t ws_size,
                              hipStream_t stream)
{
    (void)in_sizes; (void)n_in; (void)out_size; (void)ws_size;

    const float* x     = (const float*)d_in[0];
    const float* Wf    = (const float*)d_in[1];
    const float* bf    = (const float*)d_in[2];
    const float* Wg    = (const float*)d_in[3];
    const float* bg    = (const float*)d_in[4];
    const float* Wh    = (const float*)d_in[5];
    const float* bh    = (const float*)d_in[6];
    const float* Wo    = (const float*)d_in[7];
    const float* bo    = (const float*)d_in[8];
    const float* gamma = (const float*)d_in[9];
    float* out = (float*)d_out;

    // ws: f(2MB) | g(2MB) | hhT(16MB) | WThi | WTlo (~0.6MB)
    _Float16* fbuf = (_Float16*)d_ws;
    _Float16* gbuf = fbuf + (size_t)BB * NN * CKK;
    _Float16* hhT  = gbuf + (size_t)BB * NN * CKK;
    unsigned short* WThi = (unsigned short*)(hhT + (size_t)BB * CC * NN);
    unsigned short* WTlo = WThi + (size_t)576 * 256;

    prep_kernel<<<576, 256, 0, stream>>>(Wf, Wg, Wh, Wo, WThi, WTlo);
    fgh_kernel<<<BB * NN / 64, 256, 0, stream>>>(x, WThi, WTlo, bf, bg, bh,
                                                 fbuf, gbuf, hhT);
    attn_kernel<<<BB * NN / 64, 256, 0, stream>>>(fbuf, gbuf, hhT, WThi, WTlo,
                                                  bo, gamma, x, out);
}

// Round 10
// 284.424 us; speedup vs baseline: 1.6708x; 1.0506x over previous
//
#include <hip/hip_runtime.h>
#include <hip/hip_fp16.h>
#include <hip/hip_bf16.h>

constexpr int BB  = 8;
constexpr int NN  = 4096;
constexpr int CC  = 256;
constexpr int CKK = 32;

typedef __attribute__((ext_vector_type(8))) short    short8;  // 8 x bf16 bits
typedef __attribute__((ext_vector_type(8))) _Float16 half8;
typedef __attribute__((ext_vector_type(4))) _Float16 half4;
typedef __attribute__((ext_vector_type(4))) float    f32x4;

__device__ __forceinline__ unsigned short bf16_bits(float v) {
    __hip_bfloat16 h = __float2bfloat16(v);
    return *reinterpret_cast<unsigned short*>(&h);
}
__device__ __forceinline__ float bf16_val(unsigned short u) {
    __hip_bfloat16 h = *reinterpret_cast<__hip_bfloat16*>(&u);
    return __bfloat162float(h);
}

// ---------------------------------------------------------------------------
// K0: transpose + bf16 hi/lo split of all weights into WT[576][256]:
// rows 0..255 = Wh cols, 256..287 = Wf, 288..319 = Wg, 320..575 = Wo.
// ---------------------------------------------------------------------------
__global__ __launch_bounds__(256) void prep_kernel(
    const float* __restrict__ Wf, const float* __restrict__ Wg,
    const float* __restrict__ Wh, const float* __restrict__ Wo,
    unsigned short* __restrict__ WThi, unsigned short* __restrict__ WTlo)
{
    const int n = blockIdx.x;
    const int k = threadIdx.x;
    float v;
    if      (n < 256) v = Wh[k * 256 + n];
    else if (n < 288) v = Wf[k * 32 + (n - 256)];
    else if (n < 320) v = Wg[k * 32 + (n - 288)];
    else              v = Wo[k * 256 + (n - 320)];
    const unsigned short hi = bf16_bits(v);
    WThi[n * 256 + k] = hi;
    WTlo[n * 256 + k] = bf16_bits(v - bf16_val(hi));
}

// ---------------------------------------------------------------------------
// K1: projections, LDS-STAGED A (the m97-ladder lever, never tried here).
// Grid 512 (b,q0), 256 thr. All 4 waves consume the SAME 64 x-rows; before,
// each wave loaded them direct-to-reg (4x redundant traffic, ~900cy HBM
// latency naked on the critical path each k-step -> fgh ~114 us vs ~10 us
// roofline; conv-removal r4, pipelining r5, repartition r9 all ~neutral).
// Now per kc-step:
//   staged regs -> ds_write_b128 into XT[2][64][36] f32 (stride 144 B =
//   9x16B: aligned b128 reads; ln*36 = 4*ln mod 32 banks -> 2-way max,
//   free) | barrier | PREFETCH next tile to regs (flies across compute) |
//   ds_read_b128 A-frags | identical conv | identical 60-MFMA sequence.
// f32 bits survive LDS exactly -> bitwise-identical f/g/hhT.
// ---------------------------------------------------------------------------
__global__ __launch_bounds__(256) void fgh_kernel(
    const float* __restrict__ x,
    const unsigned short* __restrict__ WThi, const unsigned short* __restrict__ WTlo,
    const float* __restrict__ bf, const float* __restrict__ bg,
    const float* __restrict__ bh,
    _Float16* __restrict__ fbuf, _Float16* __restrict__ gbuf,
    _Float16* __restrict__ hhT)
{
    __shared__ __align__(16) float XT[2][64 * 36];   // 2 x 9.2 KB dbuf

    const int tid = threadIdx.x, w = tid >> 6, lane = tid & 63;
    const int ln = lane & 15, lq = lane >> 4;
    const int b  = blockIdx.x & 7;               // batch == XCD
    const int q0 = (blockIdx.x >> 3) * 64;
    const size_t px0 = (size_t)b * NN + q0;      // block's 64 pixels
    const int n0 = w * 80;                       // wave's 80 output columns

    // staging role: thread t covers row p = t/4, k-quarter jq = t%4
    const int p  = tid >> 2;
    const int jq = tid & 3;
    const float* xrow = &x[(px0 + p) * CC + jq * 8];

    f32x4 acc[4][5];   // [mt][nt]
    #pragma unroll
    for (int i = 0; i < 4; ++i)
        #pragma unroll
        for (int j = 0; j < 5; ++j) acc[i][j] = {0.f, 0.f, 0.f, 0.f};

    short8 Ahi[4], Alo[4];
    float4 ra0 = *(const float4*)&xrow[0];
    float4 ra1 = *(const float4*)&xrow[4];

    int cur = 0;
    #pragma unroll 1
    for (int kc = 0; kc < 8; ++kc) {
        const int k0 = kc * 32;
        // stage this tile from regs to LDS
        float* dst = &XT[cur][p * 36 + jq * 8];
        *(float4*)&dst[0] = ra0;
        *(float4*)&dst[4] = ra1;
        __syncthreads();
        // prefetch next tile (in flight across the whole compute phase)
        if (kc < 7) {
            ra0 = *(const float4*)&xrow[(kc + 1) * 32];
            ra1 = *(const float4*)&xrow[(kc + 1) * 32 + 4];
        }
        // A-frags from LDS + identical conversion
        #pragma unroll
        for (int mt = 0; mt < 4; ++mt) {
            float av[8];
            const float* sp = &XT[cur][(mt * 16 + ln) * 36 + lq * 8];
            *(float4*)&av[0] = *(const float4*)&sp[0];
            *(float4*)&av[4] = *(const float4*)&sp[4];
            #pragma unroll
            for (int j = 0; j < 8; ++j) {
                const unsigned short h = bf16_bits(av[j]);
                Ahi[mt][j] = (short)h;
                Alo[mt][j] = (short)bf16_bits(av[j] - bf16_val(h));
            }
        }
        #pragma unroll
        for (int nt = 0; nt < 5; ++nt) {
            const size_t boff = (size_t)(n0 + nt * 16 + ln) * 256 + k0 + lq * 8;
            const short8 Bhi = *(const short8*)&WThi[boff];
            const short8 Blo = *(const short8*)&WTlo[boff];
            #pragma unroll
            for (int mt = 0; mt < 4; ++mt) {
                acc[mt][nt] = __builtin_amdgcn_mfma_f32_16x16x32_bf16(Ahi[mt], Bhi, acc[mt][nt], 0, 0, 0);
                acc[mt][nt] = __builtin_amdgcn_mfma_f32_16x16x32_bf16(Ahi[mt], Blo, acc[mt][nt], 0, 0, 0);
                acc[mt][nt] = __builtin_amdgcn_mfma_f32_16x16x32_bf16(Alo[mt], Bhi, acc[mt][nt], 0, 0, 0);
            }
        }
        cur ^= 1;
    }

    // stores: c < 256 -> hhT (transposed fp16); 256..287 -> f; 288..319 -> g.
    #pragma unroll
    for (int nt = 0; nt < 5; ++nt) {
        const int c = n0 + nt * 16 + ln;
        if (c < 256) {
            const float bias = bh[c];
            #pragma unroll
            for (int mt = 0; mt < 4; ++mt) {
                half4 hv;
                #pragma unroll
                for (int r = 0; r < 4; ++r) hv[r] = (_Float16)(acc[mt][nt][r] + bias);
                *(half4*)&hhT[((size_t)(b * CC + c)) * NN + q0 + mt * 16 + lq * 4] = hv;
            }
        } else {
            const bool isf = (c < 288);
            const int d = isf ? (c - 256) : (c - 288);
            const float bias = isf ? bf[d] : bg[d];
            _Float16* dst2 = isf ? fbuf : gbuf;
            #pragma unroll
            for (int mt = 0; mt < 4; ++mt)
                #pragma unroll
                for (int r = 0; r < 4; ++r)
                    dst2[(px0 + mt * 16 + lq * 4 + r) * CKK + d] =
                        (_Float16)(acc[mt][nt][r] + bias);
        }
    }
}

// ---------------------------------------------------------------------------
// K2: MFMA flash attention + FUSED output GEMM (round-8/9 state, unchanged:
// 181 us, matched prediction). Block = 64 q x 256 c; 4 waves; grid 512.
// Main loop: phaseA (S^T -> exp -> P LDS dbuf) | barrier | post-barrier Bh
// prefetch | phaseB (PV, register-dbuf Bh). Epilogue: normalize O -> LDS
// OF[64][268] (aliases dead P) -> out_kernel inner loop per wave (64 out
// channels) -> gamma/bias/x epilogue. Bitwise-identical to unfused.
// ---------------------------------------------------------------------------
__global__ __launch_bounds__(256, 2) void attn_kernel(
    const _Float16* __restrict__ fbuf, const _Float16* __restrict__ gbuf,
    const _Float16* __restrict__ hhT,
    const unsigned short* __restrict__ WThi, const unsigned short* __restrict__ WTlo,
    const float* __restrict__ bo, const float* __restrict__ gamma,
    const float* __restrict__ x, float* __restrict__ out)
{
    // OF (epilogue o-staging, f32 [64][268]) aliases P (main-loop dbuf).
    __shared__ __align__(16) float OF[64 * 268];          // 68.6 KB
    _Float16* P0 = (_Float16*)OF;                          // [64*72] fp16
    _Float16* P1 = P0 + 64 * 72;
    __shared__ float mxbuf[4][64];
    __shared__ float rsbuf[4][64];

    const int tid = threadIdx.x, w = tid >> 6, lane = tid & 63;
    const int ln = lane & 15, lq = lane >> 4;
    const int b  = blockIdx.x & 7;               // batch == XCD
    const int q0 = (blockIdx.x >> 3) * 64;
    const int cb = w * 64;                       // this wave's channel base

    const f32x4 zero = {0.f, 0.f, 0.f, 0.f};
    constexpr float LOG2E = 1.4426950408889634f;

    // persistent g B-frags: B[k=d][n=q]
    half8 Bg[4];
    #pragma unroll
    for (int qt = 0; qt < 4; ++qt)
        Bg[qt] = *(const half8*)&gbuf[(size_t)(b * NN + q0 + qt * 16 + ln) * CKK + lq * 8];

    // base pointers (advance by constants inside loops)
    const _Float16* fb = &fbuf[(size_t)(b * NN + w * 16 + ln) * CKK + lq * 8];
    const _Float16* hb = &hhT[((size_t)(b * CC + cb + ln)) * NN + lq * 8];

    // ---- pass 1: rowmax (wave w covers keys j0 + w*16 + 0..15), pipelined ----
    float mx[4];
    #pragma unroll
    for (int qt = 0; qt < 4; ++qt) mx[qt] = -1e30f;
    half8 Afc = *(const half8*)fb;
    #pragma unroll 1
    for (int j0 = 0; j0 < NN; j0 += 64) {
        const int jn = (j0 + 64 < NN) ? j0 + 64 : j0;
        const half8 Afn = *(const half8*)&fb[(size_t)jn * CKK];
        #pragma unroll
        for (int qt = 0; qt < 4; ++qt) {
            const f32x4 s = __builtin_amdgcn_mfma_f32_16x16x32_f16(Afc, Bg[qt], zero, 0, 0, 0);
            mx[qt] = fmaxf(mx[qt], fmaxf(fmaxf(s[0], s[1]), fmaxf(s[2], s[3])));
        }
        Afc = Afn;
    }
    #pragma unroll
    for (int qt = 0; qt < 4; ++qt) {
        mx[qt] = fmaxf(mx[qt], __shfl_xor(mx[qt], 16));
        mx[qt] = fmaxf(mx[qt], __shfl_xor(mx[qt], 32));
    }
    if (lane < 16) {
        #pragma unroll
        for (int qt = 0; qt < 4; ++qt) mxbuf[w][qt * 16 + ln] = mx[qt];
    }
    __syncthreads();
    float mk[4];   // per-lane: q = qt*16 + ln
    #pragma unroll
    for (int qt = 0; qt < 4; ++qt)
        mk[qt] = LOG2E * fmaxf(fmaxf(mxbuf[0][qt * 16 + ln], mxbuf[1][qt * 16 + ln]),
                               fmaxf(mxbuf[2][qt * 16 + ln], mxbuf[3][qt * 16 + ln]));

    // ---- main loop ----
    f32x4 O[4][4];     // [qt][ct]
    #pragma unroll
    for (int qt = 0; qt < 4; ++qt)
        #pragma unroll
        for (int ct = 0; ct < 4; ++ct) O[qt][ct] = zero;
    float psum[4] = {0.f, 0.f, 0.f, 0.f};

    // phase A: S^T -> exp -> P (LDS); identical MFMA to pass 1
    auto phaseA = [&](const half8& Af, _Float16* Pb) {
        #pragma unroll
        for (int qt = 0; qt < 4; ++qt) {
            const f32x4 s = __builtin_amdgcn_mfma_f32_16x16x32_f16(Af, Bg[qt], zero, 0, 0, 0);
            half4 ph;
            float ps = 0.f;
            #pragma unroll
            for (int r = 0; r < 4; ++r) {
                const float p = exp2f(fmaf(s[r], LOG2E, -mk[qt]));
                ps += p;
                ph[r] = (_Float16)p;
            }
            psum[qt] += ps;
            // P[q = qt*16+ln][key = w*16 + lq*4 + r]  (A-layout, pad 72)
            *(half4*)&Pb[(qt * 16 + ln) * 72 + w * 16 + lq * 4] = ph;
        }
    };

    // issue 8 global b128 loads of hhT B-frags for key block j0
    auto loadBh = [&](half8 (&Bh)[4][2], int j0) {
        #pragma unroll
        for (int ct = 0; ct < 4; ++ct)
            #pragma unroll
            for (int kh = 0; kh < 2; ++kh)
                Bh[ct][kh] = *(const half8*)&hb[(size_t)ct * 16 * NN + j0 + kh * 32];
    };

    // phase B: PV for this wave's 64 channels, K=64 via 2 K32 halves
    auto phaseB = [&](const half8 (&Bh)[4][2], const _Float16* Pb) {
        __builtin_amdgcn_s_setprio(1);
        #pragma unroll
        for (int qt = 0; qt < 4; ++qt) {
            const half8 Ap0 = *(const half8*)&Pb[(qt * 16 + ln) * 72 + lq * 8];
            const half8 Ap1 = *(const half8*)&Pb[(qt * 16 + ln) * 72 + 32 + lq * 8];
            #pragma unroll
            for (int ct = 0; ct < 4; ++ct) {
                O[qt][ct] = __builtin_amdgcn_mfma_f32_16x16x32_f16(Ap0, Bh[ct][0], O[qt][ct], 0, 0, 0);
                O[qt][ct] = __builtin_amdgcn_mfma_f32_16x16x32_f16(Ap1, Bh[ct][1], O[qt][ct], 0, 0, 0);
            }
        }
        __builtin_amdgcn_s_setprio(0);
    };

    // prologue: current-iter buffers
    half8 Bh0[4][2], Bh1[4][2];
    half8 Af0, Af1;
    loadBh(Bh0, 0);
    Af0 = *(const half8*)fb;

    #pragma unroll 1
    for (int j0 = 0; j0 < NN; j0 += 128) {
        // --- even 64-key block: uses Bh0/Af0, prefetches Bh1/Af1 ---
        phaseA(Af0, P0);
        __syncthreads();                         // drains Bh0 (issued 1 iter ago)
        loadBh(Bh1, j0 + 64);                    // post-barrier issue: lands during
        Af1 = *(const half8*)&fb[(size_t)(j0 + 64) * CKK];  // phaseB + next phaseA
        phaseB(Bh0, P0);
        // --- odd 64-key block: uses Bh1/Af1, prefetches Bh0/Af0 ---
        phaseA(Af1, P1);
        __syncthreads();
        if (j0 + 128 < NN) {
            loadBh(Bh0, j0 + 128);
            Af0 = *(const half8*)&fb[(size_t)(j0 + 128) * CKK];
        }
        phaseB(Bh1, P1);
    }

    // ---- rowsum merge across waves ----
    #pragma unroll
    for (int qt = 0; qt < 4; ++qt) {
        psum[qt] += __shfl_xor(psum[qt], 16);
        psum[qt] += __shfl_xor(psum[qt], 32);
    }
    if (lane < 16) {
        #pragma unroll
        for (int qt = 0; qt < 4; ++qt) rsbuf[w][qt * 16 + ln] = psum[qt];
    }
    __syncthreads();   // also: all phaseB P-reads done -> P (alias OF) is dead

    // ---- stage normalized o into LDS OF[64][268] (f32, same values the
    //      old obuf held) ----
    #pragma unroll
    for (int qt = 0; qt < 4; ++qt)
        #pragma unroll
        for (int r = 0; r < 4; ++r) {
            const int q = qt * 16 + lq * 4 + r;
            const float rinv = 1.0f / (rsbuf[0][q] + rsbuf[1][q] + rsbuf[2][q] + rsbuf[3][q]);
            #pragma unroll
            for (int ct = 0; ct < 4; ++ct)
                OF[q * 268 + cb + ct * 16 + ln] = O[qt][ct][r] * rinv;
        }
    __syncthreads();

    // ---- fused out-GEMM: out[64 q][256 c] = gamma*(o @ Wo + bo) + x.
    //      Wave w handles out-channels n0 = w*64 .. +63; identical inner
    //      loop to the old out_kernel (bitwise-same accumulation). ----
    {
        const int n0 = w * 64;
        f32x4 acc[4][4];
        #pragma unroll
        for (int i = 0; i < 4; ++i)
            #pragma unroll
            for (int j = 0; j < 4; ++j) acc[i][j] = {0.f, 0.f, 0.f, 0.f};

        short8 Ahi[4], Alo[4];
        #pragma unroll 1
        for (int kc = 0; kc < 8; ++kc) {
            const int k0 = kc * 32;
            #pragma unroll
            for (int mt = 0; mt < 4; ++mt) {
                float av[8];
                *(f32x4*)&av[0] = *(const f32x4*)&OF[(mt * 16 + ln) * 268 + k0 + lq * 8];
                *(f32x4*)&av[4] = *(const f32x4*)&OF[(mt * 16 + ln) * 268 + k0 + lq * 8 + 4];
                #pragma unroll
                for (int j = 0; j < 8; ++j) {
                    const unsigned short h = bf16_bits(av[j]);
                    Ahi[mt][j] = (short)h;
                    Alo[mt][j] = (short)bf16_bits(av[j] - bf16_val(h));
                }
            }
            #pragma unroll
            for (int nt = 0; nt < 4; ++nt) {
                const size_t boff = (size_t)(320 + n0 + nt * 16 + ln) * 256 + k0 + lq * 8;
                const short8 Bhi = *(const short8*)&WThi[boff];
                const short8 Blo = *(const short8*)&WTlo[boff];
                #pragma unroll
                for (int mt = 0; mt < 4; ++mt) {
                    acc[mt][nt] = __builtin_amdgcn_mfma_f32_16x16x32_bf16(Ahi[mt], Bhi, acc[mt][nt], 0, 0, 0);
                    acc[mt][nt] = __builtin_amdgcn_mfma_f32_16x16x32_bf16(Ahi[mt], Blo, acc[mt][nt], 0, 0, 0);
                    acc[mt][nt] = __builtin_amdgcn_mfma_f32_16x16x32_bf16(Alo[mt], Bhi, acc[mt][nt], 0, 0, 0);
                }
            }
        }

        const float gm = gamma[0];
        #pragma unroll
        for (int nt = 0; nt < 4; ++nt) {
            const int c = n0 + nt * 16 + ln;
            const float bias = bo[c];
            #pragma unroll
            for (int mt = 0; mt < 4; ++mt)
                #pragma unroll
                for (int r = 0; r < 4; ++r) {
                    const size_t idx = (size_t)(b * NN + q0 + mt * 16 + lq * 4 + r) * CC + c;
                    out[idx] = gm * (acc[mt][nt][r] + bias) + x[idx];
                }
        }
    }
}

// ---------------------------------------------------------------------------
extern "C" void kernel_launch(void* const* d_in, const int* in_sizes, int n_in,
                              void* d_out, int out_size, void* d_ws, size_t ws_size,
                              hipStream_t stream)
{
    (void)in_sizes; (void)n_in; (void)out_size; (void)ws_size;

    const float* x     = (const float*)d_in[0];
    const float* Wf    = (const float*)d_in[1];
    const float* bf    = (const float*)d_in[2];
    const float* Wg    = (const float*)d_in[3];
    const float* bg    = (const float*)d_in[4];
    const float* Wh    = (const float*)d_in[5];
    const float* bh    = (const float*)d_in[6];
    const float* Wo    = (const float*)d_in[7];
    const float* bo    = (const float*)d_in[8];
    const float* gamma = (const float*)d_in[9];
    float* out = (float*)d_out;

    // ws: f(2MB) | g(2MB) | hhT(16MB) | WThi | WTlo (~0.6MB)
    _Float16* fbuf = (_Float16*)d_ws;
    _Float16* gbuf = fbuf + (size_t)BB * NN * CKK;
    _Float16* hhT  = gbuf + (size_t)BB * NN * CKK;
    unsigned short* WThi = (unsigned short*)(hhT + (size_t)BB * CC * NN);
    unsigned short* WTlo = WThi + (size_t)576 * 256;

    prep_kernel<<<576, 256, 0, stream>>>(Wf, Wg, Wh, Wo, WThi, WTlo);
    fgh_kernel<<<BB * NN / 64, 256, 0, stream>>>(x, WThi, WTlo, bf, bg, bh,
                                                 fbuf, gbuf, hhT);
    attn_kernel<<<BB * NN / 64, 256, 0, stream>>>(fbuf, gbuf, hhT, WThi, WTlo,
                                                  bo, gamma, x, out);
}